// Round 7
// baseline (321.389 us; speedup 1.0000x reference)
//
#include <hip/hip_runtime.h>

typedef __bf16 bf16;
typedef __bf16 bf16x4 __attribute__((ext_vector_type(4)));
typedef __bf16 bf16x8 __attribute__((ext_vector_type(8)));
typedef float  f32x4  __attribute__((ext_vector_type(4)));

#define MFMA16(A_, B_, C_) __builtin_amdgcn_mfma_f32_16x16x32_bf16((A_), (B_), (C_), 0, 0, 0)

// ---- constants ----
#define BB 4
#define TT 2048
#define CC 1024
#define HH 16
#define DD 64
#define MM (BB * TT)         // 8192
#define N_QKV (3 * CC)       // 3072
#define LDSS 72              // attention LDS row stride: 144 B -> every row 16B-aligned
#define BSTRIDE 36           // tier-C sB row stride
// 1/sqrt(D) * log2(e): p = exp(s/8) computed as exp2(s * QSCALE2)
#define QSCALE2 0.18033688f

// fences: raw barrier with compiler memory ordering on both sides
#define BARRIER() do { asm volatile("" ::: "memory"); \
                       __builtin_amdgcn_s_barrier();  \
                       asm volatile("" ::: "memory"); } while (0)
#define VMCNT(n)  asm volatile("s_waitcnt vmcnt(" #n ")" ::: "memory")

static __device__ __forceinline__ void store_lds8(bf16* p, bf16x8 v) {
  bf16x4 lo, hi;
#pragma unroll
  for (int i = 0; i < 4; i++) { lo[i] = v[i]; hi[i] = v[i + 4]; }
  *(bf16x4*)p = lo;
  *(bf16x4*)(p + 4) = hi;
}

static __device__ __forceinline__ bf16x8 load_lds8(const bf16* p) {
  bf16x4 lo = *(const bf16x4*)p;
  bf16x4 hi = *(const bf16x4*)(p + 4);
  bf16x8 v;
#pragma unroll
  for (int i = 0; i < 4; i++) { v[i] = lo[i]; v[i + 4] = hi[i]; }
  return v;
}

// async global->LDS, 16 B per lane; LDS dest = wave-uniform base + lane*16
static __device__ __forceinline__ void async_cp16(const bf16* g, bf16* l) {
  __builtin_amdgcn_global_load_lds(
      (const __attribute__((address_space(1))) void*)g,
      (__attribute__((address_space(3))) void*)l, 16, 0, 0);
}

// -------------------- dtype sniff --------------------
__global__ __launch_bounds__(256) void sniff_k(const unsigned short* __restrict__ u,
                                               int* __restrict__ flag) {
  __shared__ int s;
  if (threadIdx.x == 0) s = 0;
  __syncthreads();
  int c = 0;
  for (int i = threadIdx.x; i < 65536; i += 256)
    if ((u[i] & 0x7F80u) == 0x7F80u) c = 1;
  if (c) atomicOr(&s, 1);
  __syncthreads();
  if (threadIdx.x == 0) *flag = s;   // 1 = fp32 world, 0 = bf16 world
}

// -------------------- x -> bf16 convert (or copy-through), with src offset ---
__global__ __launch_bounds__(256) void cvt_k(const void* __restrict__ in,
                                             bf16* __restrict__ out,
                                             const int* __restrict__ flag,
                                             size_t off) {
  const int fl = *flag;
  const size_t i = ((size_t)blockIdx.x * 256 + threadIdx.x) * 8;
  if (fl) {
    f32x4 a = *(const f32x4*)((const float*)in + off + i);
    f32x4 b = *(const f32x4*)((const float*)in + off + i + 4);
    bf16x8 o;
#pragma unroll
    for (int j = 0; j < 4; j++) { o[j] = (bf16)a[j]; o[4 + j] = (bf16)b[j]; }
    *(bf16x8*)(out + i) = o;
  } else {
    *(bf16x8*)(out + i) = *(const bf16x8*)((const bf16*)in + off + i);
  }
}

// ------------- transpose + convert-to-bf16: out[c*R+r] = (bf16)in[r*C+c] -----
__global__ __launch_bounds__(256) void transpose_k(const void* __restrict__ in,
                                                   bf16* __restrict__ out,
                                                   int R, int C,
                                                   const int* __restrict__ flag) {
  __shared__ bf16 tile[32][33];
  const int fl = *flag;
  const int c0 = blockIdx.x * 32, r0 = blockIdx.y * 32;
  const int tx = threadIdx.x & 31, ty = threadIdx.x >> 5;
#pragma unroll
  for (int i = ty; i < 32; i += 8) {
    const size_t idx = (size_t)(r0 + i) * C + c0 + tx;
    tile[i][tx] = fl ? (bf16)((const float*)in)[idx] : ((const bf16*)in)[idx];
  }
  __syncthreads();
#pragma unroll
  for (int i = ty; i < 32; i += 8)
    out[(size_t)(c0 + i) * R + r0 + tx] = tile[tx][i];
}

// ----- V transpose: vt[bh][d][t] = V[b][t][h][d] (bf16 qkv) ------------------
__global__ __launch_bounds__(256) void vtrans_k(const bf16* __restrict__ qkv,
                                                bf16* __restrict__ vt) {
  __shared__ bf16 tile[32][33];
  const int bh = blockIdx.z;
  const int t0 = blockIdx.x * 32, d0 = blockIdx.y * 32;
  const bf16* src = qkv + (size_t)(bh >> 4) * TT * N_QKV + 2 * CC + (bh & 15) * DD;
  const int tx = threadIdx.x & 31, ty = threadIdx.x >> 5;
#pragma unroll
  for (int i = ty; i < 32; i += 8)
    tile[i][tx] = src[(size_t)(t0 + i) * N_QKV + d0 + tx];
  __syncthreads();
  bf16* dst = vt + ((size_t)bh * DD + d0) * TT + t0;
#pragma unroll
  for (int i = ty; i < 32; i += 8)
    dst[(size_t)i * TT + tx] = tile[tx][i];
}

// ===== 256x256 GEMM, m201-style quadrant phases, counted vmcnt(4) ============
// BM=BN=256, BK=64, 8 waves. Phases = BLOCK-level C-quadrants (MH,NH): all 8
// waves cooperate on one 128x128 quadrant x K=64 (16 MFMA/wave), reading ONLY
// A-half MH + B-half NH. Fragment persistence: aq reused across 2 phases,
// bq0/bq1 held across the whole tile -> ds_reads/phase = 12,4,8,0.
// LDS 128 KB: sA/sB[2 buf][2 half][128x64]. Stage unit = one half (2 gloads);
// 1 unit/phase; schedule (steady iter, tiles T=buf0, T+1=buf1):
//   p1:B0[b1,T+1] p2:A1[b1,T+1] p3:A0[b0,T+2] p4:B1[b0,T+2]
//   p5:B0[b0,T+2] p6:A1[b0,T+2] p7:A0[b1,T+3] p8:B1[b1,T+3]
// Every stage lands >=1 phase after the region's last LDS read (audited).
// vmcnt(4) at p4/p8 only: each guarantees exactly the units needed by the
// next 4 phases, issued >=4 phases earlier. Swizzle: phys chunk = logical ^
// (row&7), via pre-swizzled global source col + XOR'd read col (2-way max).
__global__ __launch_bounds__(512, 2) void gemm_q(const bf16* __restrict__ A,
                                                 const bf16* __restrict__ Bt,
                                                 bf16* __restrict__ C,
                                                 int M, int N, int K,
                                                 int lda, int ldc) {
  __shared__ __align__(16) bf16 sA[2][2][128 * 64];
  __shared__ __align__(16) bf16 sB[2][2][128 * 64];
  const int tid = threadIdx.x;
  const int lane = tid & 63, wave = tid >> 6;
  const int quad = lane >> 4, l15 = lane & 15;
  const int wm = wave >> 2, wn = wave & 3;   // 2M x 4N within a quadrant

  // bijective XCD swizzle, n fastest; grid % 8 == 0
  const int nn = N >> 8;
  const int cpx = gridDim.x >> 3;
  const int sw = ((int)blockIdx.x & 7) * cpx + ((int)blockIdx.x >> 3);
  const int m0 = (sw / nn) * 256, n0 = (sw % nn) * 256;

  const int srow = tid >> 3;                                // 0..63
  const int scol = (((tid & 7) ^ ((tid >> 3) & 7)) << 3);   // pre-swizzled col
  const int rdx = l15 & 7;                                  // read-side XOR base

  const bf16* Ag = A + (size_t)(m0 + srow) * lda + scol;
  const bf16* Bg = Bt + (size_t)(n0 + srow) * K + scol;

  f32x4 acc[2][2][4][2];   // [MH][NH][mf][nf]
#pragma unroll
  for (int a = 0; a < 2; a++)
#pragma unroll
    for (int b = 0; b < 2; b++)
#pragma unroll
      for (int c = 0; c < 4; c++)
#pragma unroll
        for (int d = 0; d < 2; d++) {
          f32x4 z = {0.f, 0.f, 0.f, 0.f};
          acc[a][b][c][d] = z;
        }

  bf16x8 aq[2][4], bq0[2][2], bq1[2][2];   // [kk][frag]

#define STG_A(b_, h_, T_) do {                                               \
    async_cp16(Ag + (size_t)((h_) * 128) * lda + (T_) * 64,                  \
               &sA[b_][h_][wave * 512]);                                     \
    async_cp16(Ag + (size_t)((h_) * 128 + 64) * lda + (T_) * 64,             \
               &sA[b_][h_][4096 + wave * 512]);                              \
  } while (0)
#define STG_B(b_, h_, T_) do {                                               \
    async_cp16(Bg + (size_t)((h_) * 128) * K + (T_) * 64,                    \
               &sB[b_][h_][wave * 512]);                                     \
    async_cp16(Bg + (size_t)((h_) * 128 + 64) * K + (T_) * 64,               \
               &sB[b_][h_][4096 + wave * 512]);                              \
  } while (0)
#define RD_A(b_, h_) do {                                                    \
    _Pragma("unroll")                                                        \
    for (int kk = 0; kk < 2; kk++)                                           \
      _Pragma("unroll")                                                      \
      for (int mf = 0; mf < 4; mf++) {                                       \
        const int r_ = wm * 64 + mf * 16 + l15;                              \
        aq[kk][mf] = *(const bf16x8*)(&sA[b_][h_][                           \
            r_ * 64 + (((kk * 4 + quad) ^ rdx) << 3)]);                      \
      }                                                                      \
  } while (0)
#define RD_B(dst_, b_, h_) do {                                              \
    _Pragma("unroll")                                                        \
    for (int kk = 0; kk < 2; kk++)                                           \
      _Pragma("unroll")                                                      \
      for (int nf = 0; nf < 2; nf++) {                                       \
        const int r_ = wn * 32 + nf * 16 + l15;                              \
        dst_[kk][nf] = *(const bf16x8*)(&sB[b_][h_][                         \
            r_ * 64 + (((kk * 4 + quad) ^ rdx) << 3)]);                      \
      }                                                                      \
  } while (0)
#define PHASE(READS_, STAGE_, MH_, NH_, BQ_, WAIT_) do {                     \
    READS_;                                                                  \
    STAGE_;                                                                  \
    BARRIER();                                                               \
    __builtin_amdgcn_s_setprio(1);                                           \
    _Pragma("unroll")                                                        \
    for (int kk = 0; kk < 2; kk++)                                           \
      _Pragma("unroll")                                                      \
      for (int mf = 0; mf < 4; mf++)                                         \
        _Pragma("unroll")                                                    \
        for (int nf = 0; nf < 2; nf++)                                       \
          acc[MH_][NH_][mf][nf] =                                            \
              MFMA16(aq[kk][mf], BQ_[kk][nf], acc[MH_][NH_][mf][nf]);        \
    __builtin_amdgcn_s_setprio(0);                                           \
    WAIT_;                                                                   \
    BARRIER();                                                               \
  } while (0)

  // ---- prologue: tile0 all 4 halves + tile1's A0,B1 ----
  STG_A(0, 0, 0); STG_B(0, 0, 0); STG_B(0, 1, 0); STG_A(0, 1, 0);
  STG_A(1, 0, 1); STG_B(1, 1, 1);
  VMCNT(4);        // tile0 landed; tile1's A0,B1 in flight
  BARRIER();

  const int NIT = K >> 7;   // iterations of 2 K-tiles (K multiple of 128)
  int T = 0;
  for (int i = 0; i < NIT - 1; i++, T += 2) {
    // tile T in buf0
    PHASE({RD_A(0, 0); RD_B(bq0, 0, 0);}, STG_B(1, 0, T + 1), 0, 0, bq0, ;);
    PHASE({RD_B(bq1, 0, 1);},             STG_A(1, 1, T + 1), 0, 1, bq1, ;);
    PHASE({RD_A(0, 1);},                  STG_A(0, 0, T + 2), 1, 1, bq1, ;);
    PHASE(;,                              STG_B(0, 1, T + 2), 1, 0, bq0, VMCNT(4));
    // tile T+1 in buf1
    PHASE({RD_A(1, 0); RD_B(bq0, 1, 0);}, STG_B(0, 0, T + 2), 0, 0, bq0, ;);
    PHASE({RD_B(bq1, 1, 1);},             STG_A(0, 1, T + 2), 0, 1, bq1, ;);
    PHASE({RD_A(1, 1);},                  STG_A(1, 0, T + 3), 1, 1, bq1, ;);
    PHASE(;,                              STG_B(1, 1, T + 3), 1, 0, bq0, VMCNT(4));
  }
  // ---- final iteration (tiles T, T+1): only T+1's B0/A1 remain to stage ----
  PHASE({RD_A(0, 0); RD_B(bq0, 0, 0);}, STG_B(1, 0, T + 1), 0, 0, bq0, ;);
  PHASE({RD_B(bq1, 0, 1);},             STG_A(1, 1, T + 1), 0, 1, bq1, ;);
  PHASE({RD_A(0, 1);},                  ;,                   1, 1, bq1, ;);
  PHASE(;,                              ;,                   1, 0, bq0, VMCNT(0));
  PHASE({RD_A(1, 0); RD_B(bq0, 1, 0);}, ;,                   0, 0, bq0, ;);
  PHASE({RD_B(bq1, 1, 1);},             ;,                   0, 1, bq1, ;);
  PHASE({RD_A(1, 1);},                  ;,                   1, 1, bq1, ;);
  PHASE(;,                              ;,                   1, 0, bq0, ;);

#undef PHASE
#undef RD_B
#undef RD_A
#undef STG_B
#undef STG_A

#pragma unroll
  for (int MH = 0; MH < 2; MH++)
#pragma unroll
    for (int NH = 0; NH < 2; NH++)
#pragma unroll
      for (int mf = 0; mf < 4; mf++)
#pragma unroll
        for (int r = 0; r < 4; r++) {
          const int m = m0 + MH * 128 + wm * 64 + mf * 16 + quad * 4 + r;
#pragma unroll
          for (int nf = 0; nf < 2; nf++) {
            const int n = n0 + NH * 128 + wn * 32 + nf * 16 + l15;
            C[(size_t)m * ldc + n] = (bf16)acc[MH][NH][mf][nf][r];
          }
        }
}

// ===== 256x128 GEMM, 4-phase/iter, uniform counted vmcnt(6) ==================
template <int EPI>
__global__ __launch_bounds__(512, 2) void gemm8p2(const bf16* __restrict__ A,
                                                  const bf16* __restrict__ Bt,
                                                  const void* __restrict__ biasv,
                                                  void* __restrict__ Cv,
                                                  const int* __restrict__ flag,
                                                  int M, int N, int K,
                                                  int lda, int ldc) {
  __shared__ __align__(16) bf16 sAb[2][2][256 * 32];
  __shared__ __align__(16) bf16 sBb[2][2][128 * 32];
  const int fl = *flag;
  const int tid = threadIdx.x;
  const int lane = tid & 63, wave = tid >> 6;
  const int quad = lane >> 4, l15 = lane & 15;
  const int wm = wave >> 1, wn = wave & 1;

  const int nn = N >> 7;
  const int cpx = gridDim.x >> 3;
  const int sw = ((int)blockIdx.x & 7) * cpx + ((int)blockIdx.x >> 3);
  const int m0 = (sw / nn) * 256, n0 = (sw % nn) * 128;

  const int srow = tid >> 2;                                // 0..127
  const int scol8 = (((tid & 3) ^ ((tid >> 3) & 3)) << 3);  // src col pre-swizzle
  const int rdcol = ((quad ^ ((l15 >> 1) & 3)) << 3);       // read-side XOR

  const bf16* Asrc = A + (size_t)(m0 + srow) * lda + scol8;
  const bf16* Bsrc = Bt + (size_t)(n0 + srow) * K + scol8;

  f32x4 acc[4][4];
#pragma unroll
  for (int i = 0; i < 4; i++)
#pragma unroll
    for (int j = 0; j < 4; j++) {
      f32x4 z = {0.f, 0.f, 0.f, 0.f};
      acc[i][j] = z;
    }

#define ST_U(buf_, kk_, k0_) do {                                          \
    async_cp16(Asrc + (k0_) + (kk_) * 32, &sAb[buf_][kk_][wave * 512]);    \
    async_cp16(Asrc + (size_t)128 * lda + (k0_) + (kk_) * 32,              \
               &sAb[buf_][kk_][4096 + wave * 512]);                        \
    async_cp16(Bsrc + (k0_) + (kk_) * 32, &sBb[buf_][kk_][wave * 512]);    \
  } while (0)

#define PH2(buf_, kk_, STAGE_, WAIT_) do {                                   \
    bf16x8 af_[4], bf_[4];                                                   \
    _Pragma("unroll")                                                        \
    for (int mf = 0; mf < 4; mf++)                                           \
      af_[mf] = *(const bf16x8*)(&sAb[buf_][kk_][                            \
          (wm * 64 + mf * 16 + l15) * 32 + rdcol]);                          \
    _Pragma("unroll")                                                        \
    for (int nf = 0; nf < 4; nf++)                                           \
      bf_[nf] = *(const bf16x8*)(&sBb[buf_][kk_][                            \
          (wn * 64 + nf * 16 + l15) * 32 + rdcol]);                          \
    STAGE_;                                                                  \
    BARRIER();                                                               \
    __builtin_amdgcn_s_setprio(1);                                           \
    _Pragma("unroll")                                                        \
    for (int mf = 0; mf < 4; mf++)                                           \
      _Pragma("unroll")                                                      \
      for (int nf = 0; nf < 4; nf++)                                         \
        acc[mf][nf] = MFMA16(af_[mf], bf_[nf], acc[mf][nf]);                 \
    __builtin_amdgcn_s_setprio(0);                                           \
    WAIT_;                                                                   \
    BARRIER();                                                               \
  } while (0)

  ST_U(0, 0, 0);
  ST_U(0, 1, 0);
  ST_U(1, 0, 64);
  VMCNT(3);
  BARRIER();

  int k0 = 0;
  const int NI = (K >> 7) - 1;
  for (int i = 0; i < NI; i++, k0 += 128) {
    PH2(0, 0, ST_U(1, 1, k0 + 64),  VMCNT(6));
    PH2(0, 1, ST_U(0, 0, k0 + 128), VMCNT(6));
    PH2(1, 0, ST_U(0, 1, k0 + 128), VMCNT(6));
    PH2(1, 1, ST_U(1, 0, k0 + 192), VMCNT(6));
  }
  PH2(0, 0, ST_U(1, 1, k0 + 64), VMCNT(3));
  PH2(0, 1, ;,                   VMCNT(0));
  PH2(1, 0, ;,                   ;);
  PH2(1, 1, ;,                   ;);

#undef PH2
#undef ST_U

#pragma unroll
  for (int mf = 0; mf < 4; mf++) {
#pragma unroll
    for (int r = 0; r < 4; r++) {
      const int m = m0 + wm * 64 + mf * 16 + quad * 4 + r;
#pragma unroll
      for (int nf = 0; nf < 4; nf++) {
        const int n = n0 + wn * 64 + nf * 16 + l15;
        float v = acc[mf][nf][r];
        const size_t idx = (size_t)m * ldc + n;
        if (EPI == 1) {
          v += fl ? ((const float*)biasv)[n] : (float)((const bf16*)biasv)[n];
          if (fl) ((float*)Cv)[idx] = v;
          else    ((bf16*)Cv)[idx] = (bf16)v;
        } else {
          ((bf16*)Cv)[idx] = (bf16)v;
        }
      }
    }
  }
}

// ----- GEMM, all-bf16, global_load_lds staging (m97 ladder step 3) -----------
template <int EPI>
__global__ __launch_bounds__(256) void gemm_lds(const bf16* __restrict__ A,
                                                const bf16* __restrict__ Bt,
                                                const void* __restrict__ biasv,
                                                void* __restrict__ Cv,
                                                const int* __restrict__ flag,
                                                size_t aoff, size_t coff,
                                                int M, int N, int K,
                                                int lda, int ldc) {
  const int fl = *flag;
  __shared__ __align__(16) bf16 sA[128 * 32];
  __shared__ __align__(16) bf16 sB[128 * 32];
  const int tid = threadIdx.x;
  const int lane = tid & 63, wave = tid >> 6;
  const int quad = lane >> 4, l15 = lane & 15;
  const int wr = wave >> 1, wc = wave & 1;
  const int m0 = blockIdx.x * 128, n0 = blockIdx.y * 128;
  const int grow = lane >> 2;         // 0..15
  const int gcol = (lane & 3) * 8;    // 0,8,16,24

  f32x4 acc[4][4];
#pragma unroll
  for (int i = 0; i < 4; i++)
#pragma unroll
    for (int j = 0; j < 4; j++) {
      f32x4 z = {0.f, 0.f, 0.f, 0.f};
      acc[i][j] = z;
    }

  const bf16* Ag = A + aoff + (size_t)(m0 + wave * 32 + grow) * lda + gcol;
  const bf16* Bg = Bt + (size_t)(n0 + wave * 32 + grow) * K + gcol;
  bf16* sAw = sA + wave * 32 * 32;
  bf16* sBw = sB + wave * 32 * 32;

  for (int k0 = 0; k0 < K; k0 += 32) {
    __syncthreads();
    async_cp16(Ag, sAw);
    async_cp16(Ag + (size_t)16 * lda, sAw + 16 * 32);
    async_cp16(Bg, sBw);
    async_cp16(Bg + (size_t)16 * K, sBw + 16 * 32);
    Ag += 32;
    Bg += 32;
    __syncthreads();

    bf16x8 af[4], bfr[4];
#pragma unroll
    for (int mi = 0; mi < 4; mi++)
      af[mi] = *(const bf16x8*)(sA + (wr * 64 + mi * 16 + l15) * 32 + quad * 8);
#pragma unroll
    for (int ni = 0; ni < 4; ni++)
      bfr[ni] = *(const bf16x8*)(sB + (wc * 64 + ni * 16 + l15) * 32 + quad * 8);
#pragma unroll
    for (int mi = 0; mi < 4; mi++)
#pragma unroll
      for (int ni = 0; ni < 4; ni++)
        acc[mi][ni] = MFMA16(af[mi], bfr[ni], acc[mi][ni]);
  }

#pragma unroll
  for (int mi = 0; mi < 4; mi++) {
#pragma unroll
    for (int r = 0; r < 4; r++) {
      const int m = m0 + wr * 64 + mi * 16 + quad * 4 + r;
#pragma unroll
      for (int ni = 0; ni < 4; ni++) {
        const int n = n0 + wc * 64 + ni * 16 + l15;
        float v = acc[mi][ni][r];
        const size_t idx = coff + (size_t)m * ldc + n;
        if (EPI == 1) {
          v += fl ? ((const float*)biasv)[n] : (float)((const bf16*)biasv)[n];
          if (fl) ((float*)Cv)[idx] = v;
          else    ((bf16*)Cv)[idx] = (bf16)v;
        } else {
          ((bf16*)Cv)[idx] = (bf16)v;
        }
      }
    }
  }
}

// ----- GEMM (B pre-transposed, register staging; A may be fp32) --------------
template <int EPI, bool AF>
__global__ __launch_bounds__(256) void gemm_bt(const void* __restrict__ Av,
                                               const bf16* __restrict__ Bt,
                                               const void* __restrict__ biasv,
                                               void* __restrict__ Cv,
                                               const int* __restrict__ flag,
                                               size_t aoff, size_t coff,
                                               int M, int N, int K,
                                               int lda, int ldc) {
  const int fl = *flag;
  const bool af32 = AF && (fl != 0);
  __shared__ __align__(16) bf16 sA[128 * 32];
  __shared__ __align__(16) bf16 sB[128 * 32];
  const int tid = threadIdx.x;
  const int lane = tid & 63, wave = tid >> 6;
  const int quad = lane >> 4, l15 = lane & 15;
  const int wr = wave >> 1, wc = wave & 1;
  const int m0 = blockIdx.x * 128, n0 = blockIdx.y * 128;
  const int srow = tid >> 2;          // 0..63
  const int scol = (tid & 3) * 8;     // 0,8,16,24

  f32x4 acc[4][4];
#pragma unroll
  for (int i = 0; i < 4; i++)
#pragma unroll
    for (int j = 0; j < 4; j++) {
      f32x4 z = {0.f, 0.f, 0.f, 0.f};
      acc[i][j] = z;
    }

  const size_t abase0 = aoff + (size_t)(m0 + srow) * lda + scol;
  const size_t abase1 = abase0 + (size_t)64 * lda;
  const bf16* Bg0 = Bt + (size_t)(n0 + srow) * K + scol;
  const bf16* Bg1 = Bg0 + (size_t)64 * K;

  for (int k0 = 0; k0 < K; k0 += 32) {
    bf16x8 a0, a1;
    if (af32) {
      const float* Af = (const float*)Av;
      f32x4 p00 = *(const f32x4*)(Af + abase0 + k0);
      f32x4 p01 = *(const f32x4*)(Af + abase0 + k0 + 4);
      f32x4 p10 = *(const f32x4*)(Af + abase1 + k0);
      f32x4 p11 = *(const f32x4*)(Af + abase1 + k0 + 4);
#pragma unroll
      for (int i = 0; i < 4; i++) {
        a0[i] = (bf16)p00[i]; a0[i + 4] = (bf16)p01[i];
        a1[i] = (bf16)p10[i]; a1[i + 4] = (bf16)p11[i];
      }
    } else {
      const bf16* Ab = (const bf16*)Av;
      a0 = *(const bf16x8*)(Ab + abase0 + k0);
      a1 = *(const bf16x8*)(Ab + abase1 + k0);
    }
    bf16x8 b0 = *(const bf16x8*)(Bg0 + k0);
    bf16x8 b1 = *(const bf16x8*)(Bg1 + k0);
    __syncthreads();
    *(bf16x8*)(sA + srow * 32 + scol) = a0;
    *(bf16x8*)(sA + (64 + srow) * 32 + scol) = a1;
    *(bf16x8*)(sB + srow * 32 + scol) = b0;
    *(bf16x8*)(sB + (64 + srow) * 32 + scol) = b1;
    __syncthreads();

    bf16x8 af[4], bfr[4];
#pragma unroll
    for (int mi = 0; mi < 4; mi++)
      af[mi] = *(const bf16x8*)(sA + (wr * 64 + mi * 16 + l15) * 32 + quad * 8);
#pragma unroll
    for (int ni = 0; ni < 4; ni++)
      bfr[ni] = *(const bf16x8*)(sB + (wc * 64 + ni * 16 + l15) * 32 + quad * 8);
#pragma unroll
    for (int mi = 0; mi < 4; mi++)
#pragma unroll
      for (int ni = 0; ni < 4; ni++)
        acc[mi][ni] = MFMA16(af[mi], bfr[ni], acc[mi][ni]);
  }

#pragma unroll
  for (int mi = 0; mi < 4; mi++) {
#pragma unroll
    for (int r = 0; r < 4; r++) {
      const int m = m0 + wr * 64 + mi * 16 + quad * 4 + r;
#pragma unroll
      for (int ni = 0; ni < 4; ni++) {
        const int n = n0 + wc * 64 + ni * 16 + l15;
        float v = acc[mi][ni][r];
        const size_t idx = coff + (size_t)m * ldc + n;
        if (EPI == 1) {
          v += fl ? ((const float*)biasv)[n] : (float)((const bf16*)biasv)[n];
          if (fl) ((float*)Cv)[idx] = v;
          else    ((bf16*)Cv)[idx] = (bf16)v;
        } else {
          ((bf16*)Cv)[idx] = (bf16)v;
        }
      }
    }
  }
}

// ----- tier-C GEMM (W row-major, in-kernel transpose staging) ----------------
template <int EPI, bool AF, bool WF>
__global__ __launch_bounds__(256) void gemm_nt(const void* __restrict__ Av,
                                               const void* __restrict__ Wv,
                                               const void* __restrict__ biasv,
                                               void* __restrict__ Cv,
                                               const int* __restrict__ flag,
                                               size_t aoff, size_t coff,
                                               int M, int N, int K,
                                               int lda, int ldc) {
  const int fl = *flag;
  const bool af32 = AF && (fl != 0);
  const bool wf32 = WF && (fl != 0);
  __shared__ __align__(16) bf16 sA[128 * 32];
  __shared__ __align__(16) bf16 sB[128 * BSTRIDE];
  const int tid = threadIdx.x;
  const int lane = tid & 63, wave = tid >> 6;
  const int quad = lane >> 4, l15 = lane & 15;
  const int wr = wave >> 1, wc = wave & 1;
  const int m0 = blockIdx.x * 128, n0 = blockIdx.y * 128;
  const int arow = tid >> 2, acol = (tid & 3) * 8;
  const int wk = tid >> 3, wn = (tid & 7) * 16;

  f32x4 acc[4][4];
#pragma unroll
  for (int i = 0; i < 4; i++)
#pragma unroll
    for (int j = 0; j < 4; j++) {
      f32x4 z = {0.f, 0.f, 0.f, 0.f};
      acc[i][j] = z;
    }

  const size_t abase0 = aoff + (size_t)(m0 + arow) * lda + acol;
  const size_t abase1 = abase0 + (size_t)64 * lda;

  for (int k0 = 0; k0 < K; k0 += 32) {
    bf16x8 a0, a1;
    if (af32) {
      const float* Af = (const float*)Av;
      f32x4 p00 = *(const f32x4*)(Af + abase0 + k0);
      f32x4 p01 = *(const f32x4*)(Af + abase0 + k0 + 4);
      f32x4 p10 = *(const f32x4*)(Af + abase1 + k0);
      f32x4 p11 = *(const f32x4*)(Af + abase1 + k0 + 4);
#pragma unroll
      for (int i = 0; i < 4; i++) {
        a0[i] = (bf16)p00[i]; a0[i + 4] = (bf16)p01[i];
        a1[i] = (bf16)p10[i]; a1[i + 4] = (bf16)p11[i];
      }
    } else {
      const bf16* Ab = (const bf16*)Av;
      a0 = *(const bf16x8*)(Ab + abase0 + k0);
      a1 = *(const bf16x8*)(Ab + abase1 + k0);
    }
    bf16 wreg[16];
    const size_t wbase = (size_t)(k0 + wk) * N + n0 + wn;
    if (wf32) {
      const float* Wf = (const float*)Wv;
      f32x4 q0 = *(const f32x4*)(Wf + wbase);
      f32x4 q1 = *(const f32x4*)(Wf + wbase + 4);
      f32x4 q2 = *(const f32x4*)(Wf + wbase + 8);
      f32x4 q3 = *(const f32x4*)(Wf + wbase + 12);
#pragma unroll
      for (int i = 0; i < 4; i++) {
        wreg[i] = (bf16)q0[i];      wreg[4 + i] = (bf16)q1[i];
        wreg[8 + i] = (bf16)q2[i];  wreg[12 + i] = (bf16)q3[i];
      }
    } else {
      const bf16* Wb = (const bf16*)Wv;
      bf16x8 w0 = *(const bf16x8*)(Wb + wbase);
      bf16x8 w1 = *(const bf16x8*)(Wb + wbase + 8);
#pragma unroll
      for (int i = 0; i < 8; i++) { wreg[i] = w0[i]; wreg[8 + i] = w1[i]; }
    }
    __syncthreads();
    *(bf16x8*)(sA + arow * 32 + acol) = a0;
    *(bf16x8*)(sA + (64 + arow) * 32 + acol) = a1;
#pragma unroll
    for (int i = 0; i < 16; i++)
      sB[(wn + i) * BSTRIDE + wk] = wreg[i];
    __syncthreads();

    bf16x8 af[4], bfr[4];
#pragma unroll
    for (int mi = 0; mi < 4; mi++)
      af[mi] = *(const bf16x8*)(sA + (wr * 64 + mi * 16 + l15) * 32 + quad * 8);
#pragma unroll
    for (int ni = 0; ni < 4; ni++)
      bfr[ni] = load_lds8(sB + (wc * 64 + ni * 16 + l15) * BSTRIDE + quad * 8);
#pragma unroll
    for (int mi = 0; mi < 4; mi++)
#pragma unroll
      for (int ni = 0; ni < 4; ni++)
        acc[mi][ni] = MFMA16(af[mi], bfr[ni], acc[mi][ni]);
  }

#pragma unroll
  for (int mi = 0; mi < 4; mi++) {
#pragma unroll
    for (int r = 0; r < 4; r++) {
      const int m = m0 + wr * 64 + mi * 16 + quad * 4 + r;
#pragma unroll
      for (int ni = 0; ni < 4; ni++) {
        const int n = n0 + wc * 64 + ni * 16 + l15;
        float v = acc[mi][ni][r];
        const size_t idx = coff + (size_t)m * ldc + n;
        if (EPI == 1) {
          v += fl ? ((const float*)biasv)[n] : (float)((const bf16*)biasv)[n];
          if (fl) ((float*)Cv)[idx] = v;
          else    ((bf16*)Cv)[idx] = (bf16)v;
        } else {
          ((bf16*)Cv)[idx] = (bf16)v;
        }
      }
    }
  }
}

// -------------------- flash attention, staged + swapped QK^T (needs vt) ------
__global__ __launch_bounds__(256) void attn_k(bf16* __restrict__ qkv,
                                              const bf16* __restrict__ vt) {
  __shared__ __align__(16) bf16 sP[128 * LDSS];   // wave-private P regions
  __shared__ __align__(16) bf16 sK[64 * LDSS];    // [key][dim]
  __shared__ __align__(16) bf16 sVt[64 * LDSS];   // [dim][key]

  const int tid = threadIdx.x;
  const int lane = tid & 63, wave = tid >> 6;
  const int quad = lane >> 4, l15 = lane & 15;
  const int bh = blockIdx.x;
  bf16* base = qkv + (size_t)(bh >> 4) * TT * N_QKV + (bh & 15) * DD;
  const bf16* Qp = base;
  const bf16* Kp = base + CC;
  const bf16* vhead = vt + (size_t)bh * DD * TT;

  const int qt = 15 - (int)blockIdx.y;   // heavy tiles dispatched first
  const int q0 = qt * 128;
  const int wave_row0 = q0 + wave * 32;
  bf16* sPw = sP + (size_t)(wave * 32) * LDSS;   // wave-private P region

  const int krow = tid >> 2;          // 0..63  (key row for K, dim row for Vt)
  const int kcol = (tid & 3) * 16;    // 0,16,32,48 (elems)

  bf16x8 ones;
  {
    const bf16 o = (l15 == 0) ? (bf16)1.0f : (bf16)0.0f;
#pragma unroll
    for (int i = 0; i < 8; i++) ones[i] = o;
  }

  // ---- Q fragments direct from global (one-time), pre-scaled ----
  bf16x8 aq[2][2];
#pragma unroll
  for (int mi = 0; mi < 2; mi++)
#pragma unroll
    for (int ks = 0; ks < 2; ks++) {
      bf16x8 v = *(const bf16x8*)(Qp + (size_t)(wave_row0 + mi * 16 + l15) * N_QKV +
                                  ks * 32 + quad * 8);
#pragma unroll
      for (int i = 0; i < 8; i++) v[i] = (bf16)((float)v[i] * QSCALE2);
      aq[mi][ks] = v;
    }

  // ---- prefetch K/V^T tile 0 into registers (coalesced) ----
  bf16x8 kr0, kr1, vr0, vr1;
  {
    const bf16* kp = Kp + (size_t)krow * N_QKV + kcol;
    kr0 = *(const bf16x8*)kp;
    kr1 = *(const bf16x8*)(kp + 8);
    const bf16* vp = vhead + (size_t)krow * TT + kcol;
    vr0 = *(const bf16x8*)vp;
    vr1 = *(const bf16x8*)(vp + 8);
  }

  f32x4 Oacc[2][4];
  f32x4 lacc[2];
#pragma unroll
  for (int mi = 0; mi < 2; mi++) {
    f32x4 z = {0.f, 0.f, 0.f, 0.f};
    lacc[mi] = z;
#pragma unroll
    for (int nt = 0; nt < 4; nt++) Oacc[mi][nt] = z;
  }

  const int jmax = q0 + 64;

  for (int j0 = 0; j0 <= jmax; j0 += 64) {
    __syncthreads();
    *(bf16x8*)(sK + krow * LDSS + kcol) = kr0;
    *(bf16x8*)(sK + krow * LDSS + kcol + 8) = kr1;
    *(bf16x8*)(sVt + krow * LDSS + kcol) = vr0;
    *(bf16x8*)(sVt + krow * LDSS + kcol + 8) = vr1;
    __syncthreads();

    if (j0 + 64 <= jmax) {          // prefetch next tile (overlaps compute)
      const bf16* kp = Kp + (size_t)(j0 + 64 + krow) * N_QKV + kcol;
      kr0 = *(const bf16x8*)kp;
      kr1 = *(const bf16x8*)(kp + 8);
      const bf16* vp = vhead + (size_t)krow * TT + j0 + 64 + kcol;
      vr0 = *(const bf16x8*)vp;
      vr1 = *(const bf16x8*)(vp + 8);
    }

    if (j0 <= wave_row0 + 31) {     // skip fully-masked tiles (wave-uniform)
      // ---- S^T = K (Q*scale)^T : swapped-operand MFMA ----
      f32x4 S[2][4];
#pragma unroll
      for (int mi = 0; mi < 2; mi++)
#pragma unroll
        for (int kt = 0; kt < 4; kt++) {
          f32x4 z = {0.f, 0.f, 0.f, 0.f};
          S[mi][kt] = z;
        }
      __builtin_amdgcn_s_setprio(1);
#pragma unroll
      for (int kt = 0; kt < 4; kt++) {
        const bf16* kp = sK + (size_t)(kt * 16 + l15) * LDSS + quad * 8;
        bf16x8 k0 = *(const bf16x8*)kp;
        bf16x8 k1 = *(const bf16x8*)(kp + 32);
        S[0][kt] = MFMA16(k0, aq[0][0], S[0][kt]);
        S[0][kt] = MFMA16(k1, aq[0][1], S[0][kt]);
        S[1][kt] = MFMA16(k0, aq[1][0], S[1][kt]);
        S[1][kt] = MFMA16(k1, aq[1][1], S[1][kt]);
      }
      __builtin_amdgcn_s_setprio(0);

      // ---- p = exp2(s), causal mask, packed b64 store (k consecutive) ----
      const bool needmask = (j0 + 63 > wave_row0);
#pragma unroll
      for (int mi = 0; mi < 2; mi++) {
        const int qg = wave_row0 + mi * 16 + l15;
#pragma unroll
        for (int kt = 0; kt < 4; kt++) {
          const int kb = j0 + kt * 16 + quad * 4;
          bf16x4 pk;
#pragma unroll
          for (int r = 0; r < 4; r++) {
            float e = __builtin_amdgcn_exp2f(S[mi][kt][r]);
            if (needmask && (kb + r > qg)) e = 0.f;
            pk[r] = (bf16)e;
          }
          *(bf16x4*)(sPw + (size_t)(mi * 16 + l15) * LDSS + kt * 16 + quad * 4) = pk;
        }
      }

      // ---- O += P V ; l += P 1 (V^T fragments from LDS) ----
      bf16x8 ap0[2], ap1[2];
#pragma unroll
      for (int mi = 0; mi < 2; mi++) {
        const bf16* pp = sPw + (size_t)(mi * 16 + l15) * LDSS + quad * 8;
        ap0[mi] = *(const bf16x8*)pp;
        ap1[mi] = *(const bf16x8*)(pp + 32);
      }
      __builtin_amdgcn_s_setprio(1);
#pragma unroll
      for (int mi = 0; mi < 2; mi++) {
        lacc[mi] = MFMA16(ap0[mi], ones, lacc[mi]);
        lacc[mi] = MFMA16(ap1[mi], ones, lacc[mi]);
      }
#pragma unroll
      for (int nt = 0; nt < 4; nt++) {
        const bf16* vp = sVt + (size_t)(nt * 16 + l15) * LDSS + quad * 8;
        bf16x8 v0 = *(const bf16x8*)vp;
        bf16x8 v1 = *(const bf16x8*)(vp + 32);
        Oacc[0][nt] = MFMA16(ap0[0], v0, Oacc[0][nt]);
        Oacc[0][nt] = MFMA16(ap1[0], v1, Oacc[0][nt]);
        Oacc[1][nt] = MFMA16(ap0[1], v0, Oacc[1][nt]);
        Oacc[1][nt] = MFMA16(ap1[1], v1, Oacc[1][nt]);
      }
      __builtin_amdgcn_s_setprio(0);
    }
  }

  // ---- epilogue ----
#pragma unroll
  for (int mi = 0; mi < 2; mi++)
#pragma unroll
    for (int r = 0; r < 4; r++) {
      const float lv = __shfl(lacc[mi][r], lane & 48, 64);
      const float invl = 1.0f / lv;
      const int t = q0 + wave * 32 + mi * 16 + quad * 4 + r;
#pragma unroll
      for (int nt = 0; nt < 4; nt++)
        base[(size_t)t * N_QKV + nt * 16 + l15] =
            (bf16)(Oacc[mi][nt][r] * invl);
    }
}

// -------------------- flash attention, staged (fallback, no vt) --------------
__global__ __launch_bounds__(256) void attn_s(bf16* __restrict__ qkv) {
  __shared__ __align__(16) bf16 sQ[128 * LDSS];   // wave regions reused for P
  __shared__ __align__(16) bf16 sK[64 * LDSS];
  __shared__ __align__(16) bf16 sVt[64 * LDSS];   // [dim][key]

  const int tid = threadIdx.x;
  const int lane = tid & 63, wave = tid >> 6;
  const int quad = lane >> 4, l15 = lane & 15;
  const int bh = blockIdx.x;
  bf16* base = qkv + (size_t)(bh >> 4) * TT * N_QKV + (bh & 15) * DD;
  const bf16* Qp = base;
  const bf16* Kp = base + CC;
  const bf16* Vp = base + 2 * CC;

  const int krow = tid >> 2;          // 0..63
  const int kcol = (tid & 3) * 16;    // 0,16,32,48
  const int vkey = tid & 31;          // 0..31
  const int vcol = (tid >> 5) * 8;    // 0..56

  bf16x8 ones;
  {
    const bf16 o = (l15 == 0) ? (bf16)1.0f : (bf16)0.0f;
#pragma unroll
    for (int i = 0; i < 8; i++) ones[i] = o;
  }

  const int qt = 15 - (int)blockIdx.y;
  const int q0 = qt * 128;

#pragma unroll
  for (int p = 0; p < 2; p++) {
    const int r = p * 64 + krow;
    const bf16* src = Qp + (size_t)(q0 + r) * N_QKV + kcol;
    bf16x8 v0 = *(const bf16x8*)src;
    bf16x8 v1 = *(const bf16x8*)(src + 8);
#pragma unroll
    for (int i = 0; i < 8; i++) {
      v0[i] = (bf16)((float)v0[i] * QSCALE2);
      v1[i] = (bf16)((float)v1[i] * QSCALE2);
    }
    *(bf16x8*)(sQ + r * LDSS + kcol) = v0;
    *(bf16x8*)(sQ + r * LDSS + kcol + 8) = v1;
  }

  bf16x8 kr0, kr1, vr0, vr1;
  {
    const bf16* kp = Kp + (size_t)krow * N_QKV + kcol;
    kr0 = *(const bf16x8*)kp;
    kr1 = *(const bf16x8*)(kp + 8);
    vr0 = *(const bf16x8*)(Vp + (size_t)vkey * N_QKV + vcol);
    vr1 = *(const bf16x8*)(Vp + (size_t)(32 + vkey) * N_QKV + vcol);
  }
  __syncthreads();

  bf16x8 aq[2][2];
#pragma unroll
  for (int mi = 0; mi < 2; mi++) {
    const bf16* qp = sQ + (size_t)(wave * 32 + mi * 16 + l15) * LDSS + quad * 8;
    aq[mi][0] = *(const bf16x8*)qp;
    aq[mi][1] = *(const bf16x8*)(qp + 32);
  }

  f32x4 Oacc[2][4];
  f32x4 lacc[2];
#pragma unroll
  for (int mi = 0; mi < 2; mi++) {
    f32x4 z = {0.f, 0.f, 0.f, 0.f};
    lacc[mi] = z;
#pragma unroll
    for (int nt = 0; nt < 4; nt++) Oacc[mi][nt] = z;
  }

  const int jmax = q0 + 64;
  const int wave_row0 = q0 + wave * 32;
  bf16* sP = sQ + (size_t)(wave * 32) * LDSS;

  for (int j0 = 0; j0 <= jmax; j0 += 64) {
    __syncthreads();
    *(bf16x8*)(sK + krow * LDSS + kcol) = kr0;
    *(bf16x8*)(sK + krow * LDSS + kcol + 8) = kr1;
#pragma unroll
    for (int i = 0; i < 8; i++) {
      sVt[(vcol + i) * LDSS + vkey] = vr0[i];
      sVt[(vcol + i) * LDSS + 32 + vkey] = vr1[i];
    }
    __syncthreads();

    if (j0 + 64 <= jmax) {
      const bf16* kp = Kp + (size_t)(j0 + 64 + krow) * N_QKV + kcol;
      kr0 = *(const bf16x8*)kp;
      kr1 = *(const bf16x8*)(kp + 8);
      vr0 = *(const bf16x8*)(Vp + (size_t)(j0 + 64 + vkey) * N_QKV + vcol);
      vr1 = *(const bf16x8*)(Vp + (size_t)(j0 + 96 + vkey) * N_QKV + vcol);
    }

    if (j0 <= wave_row0 + 31) {
      f32x4 S[2][4];
#pragma unroll
      for (int nt = 0; nt < 4; nt++) {
        const bf16* kp = sK + (size_t)(nt * 16 + l15) * LDSS + quad * 8;
        bf16x8 bk0 = *(const bf16x8*)kp;
        bf16x8 bk1 = *(const bf16x8*)(kp + 32);
#pragma unroll
        for (int mi = 0; mi < 2; mi++) {
          f32x4 acc = {0.f, 0.f, 0.f, 0.f};
          acc = MFMA16(aq[mi][0], bk0, acc);
          acc = MFMA16(aq[mi][1], bk1, acc);
          S[mi][nt] = acc;
        }
      }

      const bool needmask = (j0 + 63 > wave_row0);
#pragma unroll
      for (int mi = 0; mi < 2; mi++)
#pragma unroll
        for (int nt = 0; nt < 4; nt++) {
          const int kc = j0 + nt * 16 + l15;
#pragma unroll
          for (int r = 0; r < 4; r++) {
            float e = __builtin_amdgcn_exp2f(S[mi][nt][r]);
            if (needmask && kc > wave_row0 + mi * 16 + quad * 4 + r) e = 0.f;
            sP[(size_t)(mi * 16 + quad * 4 + r) * LDSS + nt * 16 + l15] =
                (bf16)e;
          }
        }

      bf16x8 ap[2][2];
#pragma unroll
      for (int mi = 0; mi < 2; mi++) {
        const bf16* pp = sP + (size_t)(mi * 16 + l15) * LDSS + quad * 8;
        ap[mi][0] = *(const bf16x8*)pp;
        ap[mi][1] = *(const bf16x8*)(pp + 32);
        lacc[mi] = MFMA16(ap[mi][0], ones, lacc[mi]);
        lacc[mi] = MFMA16(ap[mi][1], ones, lacc[mi]);
      }
#pragma unroll
      for (int nt = 0; nt < 4; nt++) {
        const bf16* vp = sVt + (size_t)(nt * 16 + l15) * LDSS + quad * 8;
        bf16x8 bv0 = *(const bf16x8*)vp;
        bf16x8 bv1 = *(const bf16x8*)(vp + 32);
#pragma unroll
        for (int mi = 0; mi < 2; mi++) {
          Oacc[mi][nt] = MFMA16(ap[mi][0], bv0, Oacc[mi][nt]);
          Oacc[mi][nt] = MFMA16(ap[mi][1], bv1, Oacc[mi][nt]);
        }
      }
    }
  }

#pragma unroll
  for (int mi = 0; mi < 2; mi++)
#pragma unroll
    for (int r = 0; r < 4; r++) {
      const float lv = __shfl(lacc[mi][r], lane & 48, 64);
      const float invl = 1.0f / lv;
      const int t = q0 + wave * 32 + mi * 16 + quad * 4 + r;
#pragma unroll
      for (int nt = 0; nt < 4; nt++)
        base[(size_t)t * N_QKV + nt * 16 + l15] =
            (bf16)(Oacc[mi][nt][r] * invl);
    }
}

// -------------------- launch --------------------
extern "C" void kernel_launch(void* const* d_in, const int* in_sizes, int n_in,
                              void* d_out, int out_size, void* d_ws, size_t ws_size,
                              hipStream_t stream) {
  const void* x = d_in[0];       // [8192,1024] fp32 or bf16
  const void* w_qkv = d_in[1];   // [1024,3072]
  const void* w_out = d_in[2];   // [1024,1024]
  const void* b_out = d_in[3];   // [1024]

  int* flag = (int*)d_ws;
  char* p = (char*)d_ws + 256;
  bf16* wqkvT = (bf16*)p;                          // [3072,1024]  6 MB
  bf16* woutT = wqkvT + (size_t)N_QKV * CC;        // [1024,1024]  2 MB

  const size_t wT_bytes = ((size_t)N_QKV * CC + (size_t)CC * CC) * 2;  // 8 MB
  const size_t qkv_bytes = (size_t)MM * N_QKV * 2;                     // 48 MB
  const size_t need_A = 256 + wT_bytes + qkv_bytes;                    // 56.25 MB
  const size_t need_B = 256 + wT_bytes + (size_t)TT * N_QKV * 2;

  sniff_k<<<1, 256, 0, stream>>>((const unsigned short*)x, flag);

  if (ws_size >= need_A) {
    // ---- Tier A: fused; qkv GEMM path adapts to available slack ----
    bf16* qkv = woutT + (size_t)CC * CC;
    bf16* xb = qkv + (size_t)MM * N_QKV;
    const size_t slack = ws_size - need_A;

    transpose_k<<<dim3(N_QKV / 32, CC / 32), 256, 0, stream>>>(w_qkv, wqkvT, CC, N_QKV, flag);
    transpose_k<<<dim3(CC / 32, CC / 32), 256, 0, stream>>>(w_out, woutT, CC, CC, flag);

    const size_t full_xb = (size_t)MM * CC * 2;    // 16 MB
    const size_t half_xb = full_xb / 2;            // 8 MB
    if (slack >= full_xb) {
      // single pre-convert, one 256^2 quadrant-phase GEMM; vt reuses xb after
      cvt_k<<<(MM * CC) / 2048, 256, 0, stream>>>(x, xb, flag, 0);
      gemm_q<<<dim3((MM / 256) * (N_QKV / 256)), 512, 0, stream>>>(
          xb, wqkvT, qkv, MM, N_QKV, CC, CC, N_QKV);
      bf16* vt = xb;   // 16 MB, same size as xb; xb is dead after the GEMM
      vtrans_k<<<dim3(TT / 32, DD / 32, BB * HH), 256, 0, stream>>>(qkv, vt);
      attn_k<<<dim3(BB * HH, 16), 256, 0, stream>>>(qkv, vt);
    } else if (slack >= half_xb) {
      // two 4096-row chunks
      for (int m0 = 0; m0 < MM; m0 += 4096) {
        cvt_k<<<(4096 * CC) / 2048, 256, 0, stream>>>(x, xb, flag, (size_t)m0 * CC);
        gemm_lds<0><<<dim3(4096 / 128, N_QKV / 128), 256, 0, stream>>>(
            xb, wqkvT, nullptr, qkv, flag, 0, (size_t)m0 * N_QKV,
            4096, N_QKV, CC, CC, N_QKV);
      }
      attn_s<<<dim3(BB * HH, 16), 256, 0, stream>>>(qkv);
    } else {
      // no room: fp32-A register-staged GEMM
      gemm_bt<0, true><<<dim3(MM / 128, N_QKV / 128), 256, 0, stream>>>(
          x, wqkvT, nullptr, qkv, flag, 0, 0, MM, N_QKV, CC, CC, N_QKV);
      attn_s<<<dim3(BB * HH, 16), 256, 0, stream>>>(qkv);
    }

    gemm8p2<1><<<dim3((MM / 256) * (CC / 128)), 512, 0, stream>>>(
        qkv, woutT, b_out, d_out, flag, MM, CC, CC, N_QKV, CC);
  } else if (ws_size >= need_B) {
    // ---- Tier B: per-batch, pre-transposed weights ----
    bf16* qkv = woutT + (size_t)CC * CC;
    transpose_k<<<dim3(N_QKV / 32, CC / 32), 256, 0, stream>>>(w_qkv, wqkvT, CC, N_QKV, flag);
    transpose_k<<<dim3(CC / 32, CC / 32), 256, 0, stream>>>(w_out, woutT, CC, CC, flag);
    for (int b = 0; b < BB; b++) {
      const size_t xoff = (size_t)b * TT * CC;
      gemm_bt<0, true><<<dim3(TT / 128, N_QKV / 128), 256, 0, stream>>>(
          x, wqkvT, nullptr, qkv, flag, xoff, 0, TT, N_QKV, CC, CC, N_QKV);
      attn_s<<<dim3(HH, 16), 256, 0, stream>>>(qkv);
      gemm_lds<1><<<dim3(TT / 128, CC / 128), 256, 0, stream>>>(
          qkv, woutT, b_out, d_out, flag, 0, xoff, TT, CC, CC, N_QKV, CC);
    }
  } else {
    // ---- Tier C: minimal ws ----
    bf16* qkvb = (bf16*)p;
    for (int b = 0; b < BB; b++) {
      const size_t xoff = (size_t)b * TT * CC;
      gemm_nt<0, true, true><<<dim3(TT / 128, N_QKV / 128), 256, 0, stream>>>(
          x, w_qkv, nullptr, qkvb, flag, xoff, 0, TT, N_QKV, CC, CC, N_QKV);
      attn_s<<<dim3(HH, 16), 256, 0, stream>>>(qkvb);
      gemm_nt<1, false, true><<<dim3(TT / 128, CC / 128), 256, 0, stream>>>(
          qkvb, w_out, b_out, d_out, flag, 0, xoff, TT, CC, CC, N_QKV, CC);
    }
  }
}

// Round 9
// 305.635 us; speedup vs baseline: 1.0515x; 1.0515x over previous
//
#include <hip/hip_runtime.h>

typedef __bf16 bf16;
typedef __bf16 bf16x4 __attribute__((ext_vector_type(4)));
typedef __bf16 bf16x8 __attribute__((ext_vector_type(8)));
typedef float  f32x4  __attribute__((ext_vector_type(4)));

#define MFMA16(A_, B_, C_) __builtin_amdgcn_mfma_f32_16x16x32_bf16((A_), (B_), (C_), 0, 0, 0)

// ---- constants ----
#define BB 4
#define TT 2048
#define CC 1024
#define HH 16
#define DD 64
#define MM (BB * TT)         // 8192
#define N_QKV (3 * CC)       // 3072
#define LDSS 72              // attention LDS row stride: 144 B -> every row 16B-aligned
#define BSTRIDE 36           // tier-C sB row stride
// 1/sqrt(D) * log2(e): p = exp(s/8) computed as exp2(s * QSCALE2)
#define QSCALE2 0.18033688f

// fences: raw barrier with compiler memory ordering on both sides
#define BARRIER() do { asm volatile("" ::: "memory"); \
                       __builtin_amdgcn_s_barrier();  \
                       asm volatile("" ::: "memory"); } while (0)
#define VMCNT(n)  asm volatile("s_waitcnt vmcnt(" #n ")" ::: "memory")

static __device__ __forceinline__ void store_lds8(bf16* p, bf16x8 v) {
  bf16x4 lo, hi;
#pragma unroll
  for (int i = 0; i < 4; i++) { lo[i] = v[i]; hi[i] = v[i + 4]; }
  *(bf16x4*)p = lo;
  *(bf16x4*)(p + 4) = hi;
}

static __device__ __forceinline__ bf16x8 load_lds8(const bf16* p) {
  bf16x4 lo = *(const bf16x4*)p;
  bf16x4 hi = *(const bf16x4*)(p + 4);
  bf16x8 v;
#pragma unroll
  for (int i = 0; i < 4; i++) { v[i] = lo[i]; v[i + 4] = hi[i]; }
  return v;
}

// async global->LDS, 16 B per lane; LDS dest = wave-uniform base + lane*16
static __device__ __forceinline__ void async_cp16(const bf16* g, bf16* l) {
  __builtin_amdgcn_global_load_lds(
      (const __attribute__((address_space(1))) void*)g,
      (__attribute__((address_space(3))) void*)l, 16, 0, 0);
}

// -------------------- dtype sniff --------------------
__global__ __launch_bounds__(256) void sniff_k(const unsigned short* __restrict__ u,
                                               int* __restrict__ flag) {
  __shared__ int s;
  if (threadIdx.x == 0) s = 0;
  __syncthreads();
  int c = 0;
  for (int i = threadIdx.x; i < 65536; i += 256)
    if ((u[i] & 0x7F80u) == 0x7F80u) c = 1;
  if (c) atomicOr(&s, 1);
  __syncthreads();
  if (threadIdx.x == 0) *flag = s;   // 1 = fp32 world, 0 = bf16 world
}

// -------------------- x -> bf16 convert (chunked path only) ------------------
__global__ __launch_bounds__(256) void cvt_k(const void* __restrict__ in,
                                             bf16* __restrict__ out,
                                             const int* __restrict__ flag,
                                             size_t off) {
  const int fl = *flag;
  const size_t i = ((size_t)blockIdx.x * 256 + threadIdx.x) * 8;
  if (fl) {
    f32x4 a = *(const f32x4*)((const float*)in + off + i);
    f32x4 b = *(const f32x4*)((const float*)in + off + i + 4);
    bf16x8 o;
#pragma unroll
    for (int j = 0; j < 4; j++) { o[j] = (bf16)a[j]; o[4 + j] = (bf16)b[j]; }
    *(bf16x8*)(out + i) = o;
  } else {
    *(bf16x8*)(out + i) = *(const bf16x8*)((const bf16*)in + off + i);
  }
}

// ---- fused prep: transpose w_qkv + transpose w_out (+ optional x cvt) -------
// blocks [0, 3072): wqkvT; [3072, 4096): woutT; [4096, ...): cvt x -> xb.
__global__ __launch_bounds__(256) void prep_k(const void* __restrict__ x,
                                              bf16* __restrict__ xb,
                                              const void* __restrict__ w_qkv,
                                              bf16* __restrict__ wqkvT,
                                              const void* __restrict__ w_out,
                                              bf16* __restrict__ woutT,
                                              const int* __restrict__ flag) {
  __shared__ bf16 tile[32][33];
  const int fl = *flag;
  const int b = blockIdx.x;
  const int tid = threadIdx.x;
  if (b >= 4096) {                       // ---- cvt region ----
    const size_t i = ((size_t)(b - 4096) * 256 + tid) * 8;
    if (fl) {
      f32x4 a = *(const f32x4*)((const float*)x + i);
      f32x4 c = *(const f32x4*)((const float*)x + i + 4);
      bf16x8 o;
#pragma unroll
      for (int j = 0; j < 4; j++) { o[j] = (bf16)a[j]; o[4 + j] = (bf16)c[j]; }
      *(bf16x8*)(xb + i) = o;
    } else {
      *(bf16x8*)(xb + i) = *(const bf16x8*)((const bf16*)x + i);
    }
    return;
  }
  // ---- transpose regions ----
  const void* in;
  bf16* out;
  int R, C, bx, by;
  if (b < 3072) { in = w_qkv; out = wqkvT; R = CC; C = N_QKV; bx = b % 96; by = b / 96; }
  else { const int b2 = b - 3072; in = w_out; out = woutT; R = CC; C = CC; bx = b2 % 32; by = b2 / 32; }
  const int c0 = bx * 32, r0 = by * 32;
  const int tx = tid & 31, ty = tid >> 5;
#pragma unroll
  for (int i = ty; i < 32; i += 8) {
    const size_t idx = (size_t)(r0 + i) * C + c0 + tx;
    tile[i][tx] = fl ? (bf16)((const float*)in)[idx] : ((const bf16*)in)[idx];
  }
  __syncthreads();
#pragma unroll
  for (int i = ty; i < 32; i += 8)
    out[(size_t)(c0 + i) * R + r0 + tx] = tile[tx][i];
}

// ----- V transpose: vt[bh][d][t] = V[b][t][h][d] (bf16 qkv) ------------------
__global__ __launch_bounds__(256) void vtrans_k(const bf16* __restrict__ qkv,
                                                bf16* __restrict__ vt) {
  __shared__ bf16 tile[32][33];
  const int bh = blockIdx.z;
  const int t0 = blockIdx.x * 32, d0 = blockIdx.y * 32;
  const bf16* src = qkv + (size_t)(bh >> 4) * TT * N_QKV + 2 * CC + (bh & 15) * DD;
  const int tx = threadIdx.x & 31, ty = threadIdx.x >> 5;
#pragma unroll
  for (int i = ty; i < 32; i += 8)
    tile[i][tx] = src[(size_t)(t0 + i) * N_QKV + d0 + tx];
  __syncthreads();
  bf16* dst = vt + ((size_t)bh * DD + d0) * TT + t0;
#pragma unroll
  for (int i = ty; i < 32; i += 8)
    dst[(size_t)i * TT + tx] = tile[tx][i];
}

// ===== 256x256 GEMM, m201-style quadrant phases, counted vmcnt(4) ============
__global__ __launch_bounds__(512, 2) void gemm_q(const bf16* __restrict__ A,
                                                 const bf16* __restrict__ Bt,
                                                 bf16* __restrict__ C,
                                                 int M, int N, int K,
                                                 int lda, int ldc) {
  __shared__ __align__(16) bf16 sA[2][2][128 * 64];
  __shared__ __align__(16) bf16 sB[2][2][128 * 64];
  const int tid = threadIdx.x;
  const int lane = tid & 63, wave = tid >> 6;
  const int quad = lane >> 4, l15 = lane & 15;
  const int wm = wave >> 2, wn = wave & 3;   // 2M x 4N within a quadrant

  const int nn = N >> 8;
  const int cpx = gridDim.x >> 3;
  const int sw = ((int)blockIdx.x & 7) * cpx + ((int)blockIdx.x >> 3);
  const int m0 = (sw / nn) * 256, n0 = (sw % nn) * 256;

  const int srow = tid >> 3;                                // 0..63
  const int scol = (((tid & 7) ^ ((tid >> 3) & 7)) << 3);   // pre-swizzled col
  const int rdx = l15 & 7;                                  // read-side XOR base

  const bf16* Ag = A + (size_t)(m0 + srow) * lda + scol;
  const bf16* Bg = Bt + (size_t)(n0 + srow) * K + scol;

  f32x4 acc[2][2][4][2];   // [MH][NH][mf][nf]
#pragma unroll
  for (int a = 0; a < 2; a++)
#pragma unroll
    for (int b = 0; b < 2; b++)
#pragma unroll
      for (int c = 0; c < 4; c++)
#pragma unroll
        for (int d = 0; d < 2; d++) {
          f32x4 z = {0.f, 0.f, 0.f, 0.f};
          acc[a][b][c][d] = z;
        }

  bf16x8 aq[2][4], bq0[2][2], bq1[2][2];   // [kk][frag]

#define STG_A(b_, h_, T_) do {                                               \
    async_cp16(Ag + (size_t)((h_) * 128) * lda + (T_) * 64,                  \
               &sA[b_][h_][wave * 512]);                                     \
    async_cp16(Ag + (size_t)((h_) * 128 + 64) * lda + (T_) * 64,             \
               &sA[b_][h_][4096 + wave * 512]);                              \
  } while (0)
#define STG_B(b_, h_, T_) do {                                               \
    async_cp16(Bg + (size_t)((h_) * 128) * K + (T_) * 64,                    \
               &sB[b_][h_][wave * 512]);                                     \
    async_cp16(Bg + (size_t)((h_) * 128 + 64) * K + (T_) * 64,               \
               &sB[b_][h_][4096 + wave * 512]);                              \
  } while (0)
#define RD_A(b_, h_) do {                                                    \
    _Pragma("unroll")                                                        \
    for (int kk = 0; kk < 2; kk++)                                           \
      _Pragma("unroll")                                                      \
      for (int mf = 0; mf < 4; mf++) {                                       \
        const int r_ = wm * 64 + mf * 16 + l15;                              \
        aq[kk][mf] = *(const bf16x8*)(&sA[b_][h_][                           \
            r_ * 64 + (((kk * 4 + quad) ^ rdx) << 3)]);                      \
      }                                                                      \
  } while (0)
#define RD_B(dst_, b_, h_) do {                                              \
    _Pragma("unroll")                                                        \
    for (int kk = 0; kk < 2; kk++)                                           \
      _Pragma("unroll")                                                      \
      for (int nf = 0; nf < 2; nf++) {                                       \
        const int r_ = wn * 32 + nf * 16 + l15;                              \
        dst_[kk][nf] = *(const bf16x8*)(&sB[b_][h_][                         \
            r_ * 64 + (((kk * 4 + quad) ^ rdx) << 3)]);                      \
      }                                                                      \
  } while (0)
#define PHASE(READS_, STAGE_, MH_, NH_, BQ_, WAIT_) do {                     \
    READS_;                                                                  \
    STAGE_;                                                                  \
    BARRIER();                                                               \
    __builtin_amdgcn_s_setprio(1);                                           \
    _Pragma("unroll")                                                        \
    for (int kk = 0; kk < 2; kk++)                                           \
      _Pragma("unroll")                                                      \
      for (int mf = 0; mf < 4; mf++)                                         \
        _Pragma("unroll")                                                    \
        for (int nf = 0; nf < 2; nf++)                                       \
          acc[MH_][NH_][mf][nf] =                                            \
              MFMA16(aq[kk][mf], BQ_[kk][nf], acc[MH_][NH_][mf][nf]);        \
    __builtin_amdgcn_s_setprio(0);                                           \
    WAIT_;                                                                   \
    BARRIER();                                                               \
  } while (0)

  STG_A(0, 0, 0); STG_B(0, 0, 0); STG_B(0, 1, 0); STG_A(0, 1, 0);
  STG_A(1, 0, 1); STG_B(1, 1, 1);
  VMCNT(4);
  BARRIER();

  const int NIT = K >> 7;
  int T = 0;
  for (int i = 0; i < NIT - 1; i++, T += 2) {
    PHASE({RD_A(0, 0); RD_B(bq0, 0, 0);}, STG_B(1, 0, T + 1), 0, 0, bq0, ;);
    PHASE({RD_B(bq1, 0, 1);},             STG_A(1, 1, T + 1), 0, 1, bq1, ;);
    PHASE({RD_A(0, 1);},                  STG_A(0, 0, T + 2), 1, 1, bq1, ;);
    PHASE(;,                              STG_B(0, 1, T + 2), 1, 0, bq0, VMCNT(4));
    PHASE({RD_A(1, 0); RD_B(bq0, 1, 0);}, STG_B(0, 0, T + 2), 0, 0, bq0, ;);
    PHASE({RD_B(bq1, 1, 1);},             STG_A(0, 1, T + 2), 0, 1, bq1, ;);
    PHASE({RD_A(1, 1);},                  STG_A(1, 0, T + 3), 1, 1, bq1, ;);
    PHASE(;,                              STG_B(1, 1, T + 3), 1, 0, bq0, VMCNT(4));
  }
  PHASE({RD_A(0, 0); RD_B(bq0, 0, 0);}, STG_B(1, 0, T + 1), 0, 0, bq0, ;);
  PHASE({RD_B(bq1, 0, 1);},             STG_A(1, 1, T + 1), 0, 1, bq1, ;);
  PHASE({RD_A(0, 1);},                  ;,                   1, 1, bq1, ;);
  PHASE(;,                              ;,                   1, 0, bq0, VMCNT(0));
  PHASE({RD_A(1, 0); RD_B(bq0, 1, 0);}, ;,                   0, 0, bq0, ;);
  PHASE({RD_B(bq1, 1, 1);},             ;,                   0, 1, bq1, ;);
  PHASE({RD_A(1, 1);},                  ;,                   1, 1, bq1, ;);
  PHASE(;,                              ;,                   1, 0, bq0, ;);

#undef PHASE
#undef RD_B
#undef RD_A
#undef STG_B
#undef STG_A

#pragma unroll
  for (int MH = 0; MH < 2; MH++)
#pragma unroll
    for (int NH = 0; NH < 2; NH++)
#pragma unroll
      for (int mf = 0; mf < 4; mf++)
#pragma unroll
        for (int r = 0; r < 4; r++) {
          const int m = m0 + MH * 128 + wm * 64 + mf * 16 + quad * 4 + r;
#pragma unroll
          for (int nf = 0; nf < 2; nf++) {
            const int n = n0 + NH * 128 + wn * 32 + nf * 16 + l15;
            C[(size_t)m * ldc + n] = (bf16)acc[MH][NH][mf][nf][r];
          }
        }
}

// ===== 256x128 GEMM, 4-phase/iter, uniform counted vmcnt(6) ==================
template <int EPI>
__global__ __launch_bounds__(512, 2) void gemm8p2(const bf16* __restrict__ A,
                                                  const bf16* __restrict__ Bt,
                                                  const void* __restrict__ biasv,
                                                  void* __restrict__ Cv,
                                                  const int* __restrict__ flag,
                                                  int M, int N, int K,
                                                  int lda, int ldc) {
  __shared__ __align__(16) bf16 sAb[2][2][256 * 32];
  __shared__ __align__(16) bf16 sBb[2][2][128 * 32];
  const int fl = *flag;
  const int tid = threadIdx.x;
  const int lane = tid & 63, wave = tid >> 6;
  const int quad = lane >> 4, l15 = lane & 15;
  const int wm = wave >> 1, wn = wave & 1;

  const int nn = N >> 7;
  const int cpx = gridDim.x >> 3;
  const int sw = ((int)blockIdx.x & 7) * cpx + ((int)blockIdx.x >> 3);
  const int m0 = (sw / nn) * 256, n0 = (sw % nn) * 128;

  const int srow = tid >> 2;                                // 0..127
  const int scol8 = (((tid & 3) ^ ((tid >> 3) & 3)) << 3);  // src col pre-swizzle
  const int rdcol = ((quad ^ ((l15 >> 1) & 3)) << 3);       // read-side XOR

  const bf16* Asrc = A + (size_t)(m0 + srow) * lda + scol8;
  const bf16* Bsrc = Bt + (size_t)(n0 + srow) * K + scol8;

  f32x4 acc[4][4];
#pragma unroll
  for (int i = 0; i < 4; i++)
#pragma unroll
    for (int j = 0; j < 4; j++) {
      f32x4 z = {0.f, 0.f, 0.f, 0.f};
      acc[i][j] = z;
    }

#define ST_U(buf_, kk_, k0_) do {                                          \
    async_cp16(Asrc + (k0_) + (kk_) * 32, &sAb[buf_][kk_][wave * 512]);    \
    async_cp16(Asrc + (size_t)128 * lda + (k0_) + (kk_) * 32,              \
               &sAb[buf_][kk_][4096 + wave * 512]);                        \
    async_cp16(Bsrc + (k0_) + (kk_) * 32, &sBb[buf_][kk_][wave * 512]);    \
  } while (0)

#define PH2(buf_, kk_, STAGE_, WAIT_) do {                                   \
    bf16x8 af_[4], bf_[4];                                                   \
    _Pragma("unroll")                                                        \
    for (int mf = 0; mf < 4; mf++)                                           \
      af_[mf] = *(const bf16x8*)(&sAb[buf_][kk_][                            \
          (wm * 64 + mf * 16 + l15) * 32 + rdcol]);                          \
    _Pragma("unroll")                                                        \
    for (int nf = 0; nf < 4; nf++)                                           \
      bf_[nf] = *(const bf16x8*)(&sBb[buf_][kk_][                            \
          (wn * 64 + nf * 16 + l15) * 32 + rdcol]);                          \
    STAGE_;                                                                  \
    BARRIER();                                                               \
    __builtin_amdgcn_s_setprio(1);                                           \
    _Pragma("unroll")                                                        \
    for (int mf = 0; mf < 4; mf++)                                           \
      _Pragma("unroll")                                                      \
      for (int nf = 0; nf < 4; nf++)                                         \
        acc[mf][nf] = MFMA16(af_[mf], bf_[nf], acc[mf][nf]);                 \
    __builtin_amdgcn_s_setprio(0);                                           \
    WAIT_;                                                                   \
    BARRIER();                                                               \
  } while (0)

  ST_U(0, 0, 0);
  ST_U(0, 1, 0);
  ST_U(1, 0, 64);
  VMCNT(3);
  BARRIER();

  int k0 = 0;
  const int NI = (K >> 7) - 1;
  for (int i = 0; i < NI; i++, k0 += 128) {
    PH2(0, 0, ST_U(1, 1, k0 + 64),  VMCNT(6));
    PH2(0, 1, ST_U(0, 0, k0 + 128), VMCNT(6));
    PH2(1, 0, ST_U(0, 1, k0 + 128), VMCNT(6));
    PH2(1, 1, ST_U(1, 0, k0 + 192), VMCNT(6));
  }
  PH2(0, 0, ST_U(1, 1, k0 + 64), VMCNT(3));
  PH2(0, 1, ;,                   VMCNT(0));
  PH2(1, 0, ;,                   ;);
  PH2(1, 1, ;,                   ;);

#undef PH2
#undef ST_U

#pragma unroll
  for (int mf = 0; mf < 4; mf++) {
#pragma unroll
    for (int r = 0; r < 4; r++) {
      const int m = m0 + wm * 64 + mf * 16 + quad * 4 + r;
#pragma unroll
      for (int nf = 0; nf < 4; nf++) {
        const int n = n0 + wn * 64 + nf * 16 + l15;
        float v = acc[mf][nf][r];
        const size_t idx = (size_t)m * ldc + n;
        if (EPI == 1) {
          v += fl ? ((const float*)biasv)[n] : (float)((const bf16*)biasv)[n];
          if (fl) ((float*)Cv)[idx] = v;
          else    ((bf16*)Cv)[idx] = (bf16)v;
        } else {
          ((bf16*)Cv)[idx] = (bf16)v;
        }
      }
    }
  }
}

// ----- GEMM, all-bf16, global_load_lds staging (m97 ladder step 3) -----------
template <int EPI>
__global__ __launch_bounds__(256) void gemm_lds(const bf16* __restrict__ A,
                                                const bf16* __restrict__ Bt,
                                                const void* __restrict__ biasv,
                                                void* __restrict__ Cv,
                                                const int* __restrict__ flag,
                                                size_t aoff, size_t coff,
                                                int M, int N, int K,
                                                int lda, int ldc) {
  const int fl = *flag;
  __shared__ __align__(16) bf16 sA[128 * 32];
  __shared__ __align__(16) bf16 sB[128 * 32];
  const int tid = threadIdx.x;
  const int lane = tid & 63, wave = tid >> 6;
  const int quad = lane >> 4, l15 = lane & 15;
  const int wr = wave >> 1, wc = wave & 1;
  const int m0 = blockIdx.x * 128, n0 = blockIdx.y * 128;
  const int grow = lane >> 2;         // 0..15
  const int gcol = (lane & 3) * 8;    // 0,8,16,24

  f32x4 acc[4][4];
#pragma unroll
  for (int i = 0; i < 4; i++)
#pragma unroll
    for (int j = 0; j < 4; j++) {
      f32x4 z = {0.f, 0.f, 0.f, 0.f};
      acc[i][j] = z;
    }

  const bf16* Ag = A + aoff + (size_t)(m0 + wave * 32 + grow) * lda + gcol;
  const bf16* Bg = Bt + (size_t)(n0 + wave * 32 + grow) * K + gcol;
  bf16* sAw = sA + wave * 32 * 32;
  bf16* sBw = sB + wave * 32 * 32;

  for (int k0 = 0; k0 < K; k0 += 32) {
    __syncthreads();
    async_cp16(Ag, sAw);
    async_cp16(Ag + (size_t)16 * lda, sAw + 16 * 32);
    async_cp16(Bg, sBw);
    async_cp16(Bg + (size_t)16 * K, sBw + 16 * 32);
    Ag += 32;
    Bg += 32;
    __syncthreads();

    bf16x8 af[4], bfr[4];
#pragma unroll
    for (int mi = 0; mi < 4; mi++)
      af[mi] = *(const bf16x8*)(sA + (wr * 64 + mi * 16 + l15) * 32 + quad * 8);
#pragma unroll
    for (int ni = 0; ni < 4; ni++)
      bfr[ni] = *(const bf16x8*)(sB + (wc * 64 + ni * 16 + l15) * 32 + quad * 8);
#pragma unroll
    for (int mi = 0; mi < 4; mi++)
#pragma unroll
      for (int ni = 0; ni < 4; ni++)
        acc[mi][ni] = MFMA16(af[mi], bfr[ni], acc[mi][ni]);
  }

#pragma unroll
  for (int mi = 0; mi < 4; mi++) {
#pragma unroll
    for (int r = 0; r < 4; r++) {
      const int m = m0 + wr * 64 + mi * 16 + quad * 4 + r;
#pragma unroll
      for (int ni = 0; ni < 4; ni++) {
        const int n = n0 + wc * 64 + ni * 16 + l15;
        float v = acc[mi][ni][r];
        const size_t idx = coff + (size_t)m * ldc + n;
        if (EPI == 1) {
          v += fl ? ((const float*)biasv)[n] : (float)((const bf16*)biasv)[n];
          if (fl) ((float*)Cv)[idx] = v;
          else    ((bf16*)Cv)[idx] = (bf16)v;
        } else {
          ((bf16*)Cv)[idx] = (bf16)v;
        }
      }
    }
  }
}

// ----- GEMM (B pre-transposed, register staging; A may be fp32) --------------
template <int EPI, bool AF>
__global__ __launch_bounds__(256) void gemm_bt(const void* __restrict__ Av,
                                               const bf16* __restrict__ Bt,
                                               const void* __restrict__ biasv,
                                               void* __restrict__ Cv,
                                               const int* __restrict__ flag,
                                               size_t aoff, size_t coff,
                                               int M, int N, int K,
                                               int lda, int ldc) {
  const int fl = *flag;
  const bool af32 = AF && (fl != 0);
  __shared__ __align__(16) bf16 sA[128 * 32];
  __shared__ __align__(16) bf16 sB[128 * 32];
  const int tid = threadIdx.x;
  const int lane = tid & 63, wave = tid >> 6;
  const int quad = lane >> 4, l15 = lane & 15;
  const int wr = wave >> 1, wc = wave & 1;
  const int m0 = blockIdx.x * 128, n0 = blockIdx.y * 128;
  const int srow = tid >> 2;          // 0..63
  const int scol = (tid & 3) * 8;     // 0,8,16,24

  f32x4 acc[4][4];
#pragma unroll
  for (int i = 0; i < 4; i++)
#pragma unroll
    for (int j = 0; j < 4; j++) {
      f32x4 z = {0.f, 0.f, 0.f, 0.f};
      acc[i][j] = z;
    }

  const size_t abase0 = aoff + (size_t)(m0 + srow) * lda + scol;
  const size_t abase1 = abase0 + (size_t)64 * lda;
  const bf16* Bg0 = Bt + (size_t)(n0 + srow) * K + scol;
  const bf16* Bg1 = Bg0 + (size_t)64 * K;

  for (int k0 = 0; k0 < K; k0 += 32) {
    bf16x8 a0, a1;
    if (af32) {
      const float* Af = (const float*)Av;
      f32x4 p00 = *(const f32x4*)(Af + abase0 + k0);
      f32x4 p01 = *(const f32x4*)(Af + abase0 + k0 + 4);
      f32x4 p10 = *(const f32x4*)(Af + abase1 + k0);
      f32x4 p11 = *(const f32x4*)(Af + abase1 + k0 + 4);
#pragma unroll
      for (int i = 0; i < 4; i++) {
        a0[i] = (bf16)p00[i]; a0[i + 4] = (bf16)p01[i];
        a1[i] = (bf16)p10[i]; a1[i + 4] = (bf16)p11[i];
      }
    } else {
      const bf16* Ab = (const bf16*)Av;
      a0 = *(const bf16x8*)(Ab + abase0 + k0);
      a1 = *(const bf16x8*)(Ab + abase1 + k0);
    }
    bf16x8 b0 = *(const bf16x8*)(Bg0 + k0);
    bf16x8 b1 = *(const bf16x8*)(Bg1 + k0);
    __syncthreads();
    *(bf16x8*)(sA + srow * 32 + scol) = a0;
    *(bf16x8*)(sA + (64 + srow) * 32 + scol) = a1;
    *(bf16x8*)(sB + srow * 32 + scol) = b0;
    *(bf16x8*)(sB + (64 + srow) * 32 + scol) = b1;
    __syncthreads();

    bf16x8 af[4], bfr[4];
#pragma unroll
    for (int mi = 0; mi < 4; mi++)
      af[mi] = *(const bf16x8*)(sA + (wr * 64 + mi * 16 + l15) * 32 + quad * 8);
#pragma unroll
    for (int ni = 0; ni < 4; ni++)
      bfr[ni] = *(const bf16x8*)(sB + (wc * 64 + ni * 16 + l15) * 32 + quad * 8);
#pragma unroll
    for (int mi = 0; mi < 4; mi++)
#pragma unroll
      for (int ni = 0; ni < 4; ni++)
        acc[mi][ni] = MFMA16(af[mi], bfr[ni], acc[mi][ni]);
  }

#pragma unroll
  for (int mi = 0; mi < 4; mi++) {
#pragma unroll
    for (int r = 0; r < 4; r++) {
      const int m = m0 + wr * 64 + mi * 16 + quad * 4 + r;
#pragma unroll
      for (int ni = 0; ni < 4; ni++) {
        const int n = n0 + wc * 64 + ni * 16 + l15;
        float v = acc[mi][ni][r];
        const size_t idx = coff + (size_t)m * ldc + n;
        if (EPI == 1) {
          v += fl ? ((const float*)biasv)[n] : (float)((const bf16*)biasv)[n];
          if (fl) ((float*)Cv)[idx] = v;
          else    ((bf16*)Cv)[idx] = (bf16)v;
        } else {
          ((bf16*)Cv)[idx] = (bf16)v;
        }
      }
    }
  }
}

// ----- tier-C GEMM (W row-major, in-kernel transpose staging) ----------------
template <int EPI, bool AF, bool WF>
__global__ __launch_bounds__(256) void gemm_nt(const void* __restrict__ Av,
                                               const void* __restrict__ Wv,
                                               const void* __restrict__ biasv,
                                               void* __restrict__ Cv,
                                               const int* __restrict__ flag,
                                               size_t aoff, size_t coff,
                                               int M, int N, int K,
                                               int lda, int ldc) {
  const int fl = *flag;
  const bool af32 = AF && (fl != 0);
  const bool wf32 = WF && (fl != 0);
  __shared__ __align__(16) bf16 sA[128 * 32];
  __shared__ __align__(16) bf16 sB[128 * BSTRIDE];
  const int tid = threadIdx.x;
  const int lane = tid & 63, wave = tid >> 6;
  const int quad = lane >> 4, l15 = lane & 15;
  const int wr = wave >> 1, wc = wave & 1;
  const int m0 = blockIdx.x * 128, n0 = blockIdx.y * 128;
  const int arow = tid >> 2, acol = (tid & 3) * 8;
  const int wk = tid >> 3, wn = (tid & 7) * 16;

  f32x4 acc[4][4];
#pragma unroll
  for (int i = 0; i < 4; i++)
#pragma unroll
    for (int j = 0; j < 4; j++) {
      f32x4 z = {0.f, 0.f, 0.f, 0.f};
      acc[i][j] = z;
    }

  const size_t abase0 = aoff + (size_t)(m0 + arow) * lda + acol;
  const size_t abase1 = abase0 + (size_t)64 * lda;

  for (int k0 = 0; k0 < K; k0 += 32) {
    bf16x8 a0, a1;
    if (af32) {
      const float* Af = (const float*)Av;
      f32x4 p00 = *(const f32x4*)(Af + abase0 + k0);
      f32x4 p01 = *(const f32x4*)(Af + abase0 + k0 + 4);
      f32x4 p10 = *(const f32x4*)(Af + abase1 + k0);
      f32x4 p11 = *(const f32x4*)(Af + abase1 + k0 + 4);
#pragma unroll
      for (int i = 0; i < 4; i++) {
        a0[i] = (bf16)p00[i]; a0[i + 4] = (bf16)p01[i];
        a1[i] = (bf16)p10[i]; a1[i + 4] = (bf16)p11[i];
      }
    } else {
      const bf16* Ab = (const bf16*)Av;
      a0 = *(const bf16x8*)(Ab + abase0 + k0);
      a1 = *(const bf16x8*)(Ab + abase1 + k0);
    }
    bf16 wreg[16];
    const size_t wbase = (size_t)(k0 + wk) * N + n0 + wn;
    if (wf32) {
      const float* Wf = (const float*)Wv;
      f32x4 q0 = *(const f32x4*)(Wf + wbase);
      f32x4 q1 = *(const f32x4*)(Wf + wbase + 4);
      f32x4 q2 = *(const f32x4*)(Wf + wbase + 8);
      f32x4 q3 = *(const f32x4*)(Wf + wbase + 12);
#pragma unroll
      for (int i = 0; i < 4; i++) {
        wreg[i] = (bf16)q0[i];      wreg[4 + i] = (bf16)q1[i];
        wreg[8 + i] = (bf16)q2[i];  wreg[12 + i] = (bf16)q3[i];
      }
    } else {
      const bf16* Wb = (const bf16*)Wv;
      bf16x8 w0 = *(const bf16x8*)(Wb + wbase);
      bf16x8 w1 = *(const bf16x8*)(Wb + wbase + 8);
#pragma unroll
      for (int i = 0; i < 8; i++) { wreg[i] = w0[i]; wreg[8 + i] = w1[i]; }
    }
    __syncthreads();
    *(bf16x8*)(sA + arow * 32 + acol) = a0;
    *(bf16x8*)(sA + (64 + arow) * 32 + acol) = a1;
#pragma unroll
    for (int i = 0; i < 16; i++)
      sB[(wn + i) * BSTRIDE + wk] = wreg[i];
    __syncthreads();

    bf16x8 af[4], bfr[4];
#pragma unroll
    for (int mi = 0; mi < 4; mi++)
      af[mi] = *(const bf16x8*)(sA + (wr * 64 + mi * 16 + l15) * 32 + quad * 8);
#pragma unroll
    for (int ni = 0; ni < 4; ni++)
      bfr[ni] = load_lds8(sB + (wc * 64 + ni * 16 + l15) * BSTRIDE + quad * 8);
#pragma unroll
    for (int mi = 0; mi < 4; mi++)
#pragma unroll
      for (int ni = 0; ni < 4; ni++)
        acc[mi][ni] = MFMA16(af[mi], bfr[ni], acc[mi][ni]);
  }

#pragma unroll
  for (int mi = 0; mi < 4; mi++) {
#pragma unroll
    for (int r = 0; r < 4; r++) {
      const int m = m0 + wr * 64 + mi * 16 + quad * 4 + r;
#pragma unroll
      for (int ni = 0; ni < 4; ni++) {
        const int n = n0 + wc * 64 + ni * 16 + l15;
        float v = acc[mi][ni][r];
        const size_t idx = coff + (size_t)m * ldc + n;
        if (EPI == 1) {
          v += fl ? ((const float*)biasv)[n] : (float)((const bf16*)biasv)[n];
          if (fl) ((float*)Cv)[idx] = v;
          else    ((bf16*)Cv)[idx] = (bf16)v;
        } else {
          ((bf16*)Cv)[idx] = (bf16)v;
        }
      }
    }
  }
}

// -------------------- flash attention, staged + swapped QK^T (needs vt) ------
__global__ __launch_bounds__(256) void attn_k(bf16* __restrict__ qkv,
                                              const bf16* __restrict__ vt) {
  __shared__ __align__(16) bf16 sP[128 * LDSS];   // wave-private P regions
  __shared__ __align__(16) bf16 sK[64 * LDSS];    // [key][dim]
  __shared__ __align__(16) bf16 sVt[64 * LDSS];   // [dim][key]

  const int tid = threadIdx.x;
  const int lane = tid & 63, wave = tid >> 6;
  const int quad = lane >> 4, l15 = lane & 15;
  const int bh = blockIdx.x;
  bf16* base = qkv + (size_t)(bh >> 4) * TT * N_QKV + (bh & 15) * DD;
  const bf16* Qp = base;
  const bf16* Kp = base + CC;
  const bf16* vhead = vt + (size_t)bh * DD * TT;

  const int qt = 15 - (int)blockIdx.y;   // heavy tiles dispatched first
  const int q0 = qt * 128;
  const int wave_row0 = q0 + wave * 32;
  bf16* sPw = sP + (size_t)(wave * 32) * LDSS;   // wave-private P region

  const int krow = tid >> 2;          // 0..63  (key row for K, dim row for Vt)
  const int kcol = (tid & 3) * 16;    // 0,16,32,48 (elems)

  bf16x8 ones;
  {
    const bf16 o = (l15 == 0) ? (bf16)1.0f : (bf16)0.0f;
#pragma unroll
    for (int i = 0; i < 8; i++) ones[i] = o;
  }

  // ---- Q fragments direct from global (one-time), pre-scaled ----
  bf16x8 aq[2][2];
#pragma unroll
  for (int mi = 0; mi < 2; mi++)
#pragma unroll
    for (int ks = 0; ks < 2; ks++) {
      bf16x8 v = *(const bf16x8*)(Qp + (size_t)(wave_row0 + mi * 16 + l15) * N_QKV +
                                  ks * 32 + quad * 8);
#pragma unroll
      for (int i = 0; i < 8; i++) v[i] = (bf16)((float)v[i] * QSCALE2);
      aq[mi][ks] = v;
    }

  // ---- prefetch K/V^T tile 0 into registers (coalesced) ----
  bf16x8 kr0, kr1, vr0, vr1;
  {
    const bf16* kp = Kp + (size_t)krow * N_QKV + kcol;
    kr0 = *(const bf16x8*)kp;
    kr1 = *(const bf16x8*)(kp + 8);
    const bf16* vp = vhead + (size_t)krow * TT + kcol;
    vr0 = *(const bf16x8*)vp;
    vr1 = *(const bf16x8*)(vp + 8);
  }

  f32x4 Oacc[2][4];
  f32x4 lacc[2];
#pragma unroll
  for (int mi = 0; mi < 2; mi++) {
    f32x4 z = {0.f, 0.f, 0.f, 0.f};
    lacc[mi] = z;
#pragma unroll
    for (int nt = 0; nt < 4; nt++) Oacc[mi][nt] = z;
  }

  const int jmax = q0 + 64;

  for (int j0 = 0; j0 <= jmax; j0 += 64) {
    __syncthreads();
    *(bf16x8*)(sK + krow * LDSS + kcol) = kr0;
    *(bf16x8*)(sK + krow * LDSS + kcol + 8) = kr1;
    *(bf16x8*)(sVt + krow * LDSS + kcol) = vr0;
    *(bf16x8*)(sVt + krow * LDSS + kcol + 8) = vr1;
    __syncthreads();

    if (j0 + 64 <= jmax) {          // prefetch next tile (overlaps compute)
      const bf16* kp = Kp + (size_t)(j0 + 64 + krow) * N_QKV + kcol;
      kr0 = *(const bf16x8*)kp;
      kr1 = *(const bf16x8*)(kp + 8);
      const bf16* vp = vhead + (size_t)krow * TT + j0 + 64 + kcol;
      vr0 = *(const bf16x8*)vp;
      vr1 = *(const bf16x8*)(vp + 8);
    }

    if (j0 <= wave_row0 + 31) {     // skip fully-masked tiles (wave-uniform)
      // ---- S^T = K (Q*scale)^T : swapped-operand MFMA ----
      f32x4 S[2][4];
#pragma unroll
      for (int mi = 0; mi < 2; mi++)
#pragma unroll
        for (int kt = 0; kt < 4; kt++) {
          f32x4 z = {0.f, 0.f, 0.f, 0.f};
          S[mi][kt] = z;
        }
      __builtin_amdgcn_s_setprio(1);
#pragma unroll
      for (int kt = 0; kt < 4; kt++) {
        const bf16* kp = sK + (size_t)(kt * 16 + l15) * LDSS + quad * 8;
        bf16x8 k0 = *(const bf16x8*)kp;
        bf16x8 k1 = *(const bf16x8*)(kp + 32);
        S[0][kt] = MFMA16(k0, aq[0][0], S[0][kt]);
        S[0][kt] = MFMA16(k1, aq[0][1], S[0][kt]);
        S[1][kt] = MFMA16(k0, aq[1][0], S[1][kt]);
        S[1][kt] = MFMA16(k1, aq[1][1], S[1][kt]);
      }
      __builtin_amdgcn_s_setprio(0);

      // ---- p = exp2(s), causal mask, packed b64 store (k consecutive) ----
      const bool needmask = (j0 + 63 > wave_row0);
#pragma unroll
      for (int mi = 0; mi < 2; mi++) {
        const int qg = wave_row0 + mi * 16 + l15;
#pragma unroll
        for (int kt = 0; kt < 4; kt++) {
          const int kb = j0 + kt * 16 + quad * 4;
          bf16x4 pk;
#pragma unroll
          for (int r = 0; r < 4; r++) {
            float e = __builtin_amdgcn_exp2f(S[mi][kt][r]);
            if (needmask && (kb + r > qg)) e = 0.f;
            pk[r] = (bf16)e;
          }
          *(bf16x4*)(sPw + (size_t)(mi * 16 + l15) * LDSS + kt * 16 + quad * 4) = pk;
        }
      }

      // ---- O += P V ; l += P 1 (V^T fragments from LDS) ----
      bf16x8 ap0[2], ap1[2];
#pragma unroll
      for (int mi = 0; mi < 2; mi++) {
        const bf16* pp = sPw + (size_t)(mi * 16 + l15) * LDSS + quad * 8;
        ap0[mi] = *(const bf16x8*)pp;
        ap1[mi] = *(const bf16x8*)(pp + 32);
      }
      __builtin_amdgcn_s_setprio(1);
#pragma unroll
      for (int mi = 0; mi < 2; mi++) {
        lacc[mi] = MFMA16(ap0[mi], ones, lacc[mi]);
        lacc[mi] = MFMA16(ap1[mi], ones, lacc[mi]);
      }
#pragma unroll
      for (int nt = 0; nt < 4; nt++) {
        const bf16* vp = sVt + (size_t)(nt * 16 + l15) * LDSS + quad * 8;
        bf16x8 v0 = *(const bf16x8*)vp;
        bf16x8 v1 = *(const bf16x8*)(vp + 32);
        Oacc[0][nt] = MFMA16(ap0[0], v0, Oacc[0][nt]);
        Oacc[0][nt] = MFMA16(ap1[0], v1, Oacc[0][nt]);
        Oacc[1][nt] = MFMA16(ap0[1], v0, Oacc[1][nt]);
        Oacc[1][nt] = MFMA16(ap1[1], v1, Oacc[1][nt]);
      }
      __builtin_amdgcn_s_setprio(0);
    }
  }

  // ---- epilogue ----
#pragma unroll
  for (int mi = 0; mi < 2; mi++)
#pragma unroll
    for (int r = 0; r < 4; r++) {
      const float lv = __shfl(lacc[mi][r], lane & 48, 64);
      const float invl = 1.0f / lv;
      const int t = q0 + wave * 32 + mi * 16 + quad * 4 + r;
#pragma unroll
      for (int nt = 0; nt < 4; nt++)
        base[(size_t)t * N_QKV + nt * 16 + l15] =
            (bf16)(Oacc[mi][nt][r] * invl);
    }
}

// -------------------- flash attention, staged (fallback, no vt) --------------
__global__ __launch_bounds__(256) void attn_s(bf16* __restrict__ qkv) {
  __shared__ __align__(16) bf16 sQ[128 * LDSS];   // wave regions reused for P
  __shared__ __align__(16) bf16 sK[64 * LDSS];
  __shared__ __align__(16) bf16 sVt[64 * LDSS];   // [dim][key]

  const int tid = threadIdx.x;
  const int lane = tid & 63, wave = tid >> 6;
  const int quad = lane >> 4, l15 = lane & 15;
  const int bh = blockIdx.x;
  bf16* base = qkv + (size_t)(bh >> 4) * TT * N_QKV + (bh & 15) * DD;
  const bf16* Qp = base;
  const bf16* Kp = base + CC;
  const bf16* Vp = base + 2 * CC;

  const int krow = tid >> 2;          // 0..63
  const int kcol = (tid & 3) * 16;    // 0,16,32,48
  const int vkey = tid & 31;          // 0..31
  const int vcol = (tid >> 5) * 8;    // 0..56

  bf16x8 ones;
  {
    const bf16 o = (l15 == 0) ? (bf16)1.0f : (bf16)0.0f;
#pragma unroll
    for (int i = 0; i < 8; i++) ones[i] = o;
  }

  const int qt = 15 - (int)blockIdx.y;
  const int q0 = qt * 128;

#pragma unroll
  for (int p = 0; p < 2; p++) {
    const int r = p * 64 + krow;
    const bf16* src = Qp + (size_t)(q0 + r) * N_QKV + kcol;
    bf16x8 v0 = *(const bf16x8*)src;
    bf16x8 v1 = *(const bf16x8*)(src + 8);
#pragma unroll
    for (int i = 0; i < 8; i++) {
      v0[i] = (bf16)((float)v0[i] * QSCALE2);
      v1[i] = (bf16)((float)v1[i] * QSCALE2);
    }
    *(bf16x8*)(sQ + r * LDSS + kcol) = v0;
    *(bf16x8*)(sQ + r * LDSS + kcol + 8) = v1;
  }

  bf16x8 kr0, kr1, vr0, vr1;
  {
    const bf16* kp = Kp + (size_t)krow * N_QKV + kcol;
    kr0 = *(const bf16x8*)kp;
    kr1 = *(const bf16x8*)(kp + 8);
    vr0 = *(const bf16x8*)(Vp + (size_t)vkey * N_QKV + vcol);
    vr1 = *(const bf16x8*)(Vp + (size_t)(32 + vkey) * N_QKV + vcol);
  }
  __syncthreads();

  bf16x8 aq[2][2];
#pragma unroll
  for (int mi = 0; mi < 2; mi++) {
    const bf16* qp = sQ + (size_t)(wave * 32 + mi * 16 + l15) * LDSS + quad * 8;
    aq[mi][0] = *(const bf16x8*)qp;
    aq[mi][1] = *(const bf16x8*)(qp + 32);
  }

  f32x4 Oacc[2][4];
  f32x4 lacc[2];
#pragma unroll
  for (int mi = 0; mi < 2; mi++) {
    f32x4 z = {0.f, 0.f, 0.f, 0.f};
    lacc[mi] = z;
#pragma unroll
    for (int nt = 0; nt < 4; nt++) Oacc[mi][nt] = z;
  }

  const int jmax = q0 + 64;
  const int wave_row0 = q0 + wave * 32;
  bf16* sP = sQ + (size_t)(wave * 32) * LDSS;

  for (int j0 = 0; j0 <= jmax; j0 += 64) {
    __syncthreads();
    *(bf16x8*)(sK + krow * LDSS + kcol) = kr0;
    *(bf16x8*)(sK + krow * LDSS + kcol + 8) = kr1;
#pragma unroll
    for (int i = 0; i < 8; i++) {
      sVt[(vcol + i) * LDSS + vkey] = vr0[i];
      sVt[(vcol + i) * LDSS + 32 + vkey] = vr1[i];
    }
    __syncthreads();

    if (j0 + 64 <= jmax) {
      const bf16* kp = Kp + (size_t)(j0 + 64 + krow) * N_QKV + kcol;
      kr0 = *(const bf16x8*)kp;
      kr1 = *(const bf16x8*)(kp + 8);
      vr0 = *(const bf16x8*)(Vp + (size_t)(j0 + 64 + vkey) * N_QKV + vcol);
      vr1 = *(const bf16x8*)(Vp + (size_t)(j0 + 96 + vkey) * N_QKV + vcol);
    }

    if (j0 <= wave_row0 + 31) {
      f32x4 S[2][4];
#pragma unroll
      for (int nt = 0; nt < 4; nt++) {
        const bf16* kp = sK + (size_t)(nt * 16 + l15) * LDSS + quad * 8;
        bf16x8 bk0 = *(const bf16x8*)kp;
        bf16x8 bk1 = *(const bf16x8*)(kp + 32);
#pragma unroll
        for (int mi = 0; mi < 2; mi++) {
          f32x4 acc = {0.f, 0.f, 0.f, 0.f};
          acc = MFMA16(aq[mi][0], bk0, acc);
          acc = MFMA16(aq[mi][1], bk1, acc);
          S[mi][nt] = acc;
        }
      }

      const bool needmask = (j0 + 63 > wave_row0);
#pragma unroll
      for (int mi = 0; mi < 2; mi++)
#pragma unroll
        for (int nt = 0; nt < 4; nt++) {
          const int kc = j0 + nt * 16 + l15;
#pragma unroll
          for (int r = 0; r < 4; r++) {
            float e = __builtin_amdgcn_exp2f(S[mi][nt][r]);
            if (needmask && kc > wave_row0 + mi * 16 + quad * 4 + r) e = 0.f;
            sP[(size_t)(mi * 16 + quad * 4 + r) * LDSS + nt * 16 + l15] =
                (bf16)e;
          }
        }

      bf16x8 ap[2][2];
#pragma unroll
      for (int mi = 0; mi < 2; mi++) {
        const bf16* pp = sP + (size_t)(mi * 16 + l15) * LDSS + quad * 8;
        ap[mi][0] = *(const bf16x8*)pp;
        ap[mi][1] = *(const bf16x8*)(pp + 32);
        lacc[mi] = MFMA16(ap[mi][0], ones, lacc[mi]);
        lacc[mi] = MFMA16(ap[mi][1], ones, lacc[mi]);
      }
#pragma unroll
      for (int nt = 0; nt < 4; nt++) {
        const bf16* vp = sVt + (size_t)(nt * 16 + l15) * LDSS + quad * 8;
        bf16x8 bv0 = *(const bf16x8*)vp;
        bf16x8 bv1 = *(const bf16x8*)(vp + 32);
#pragma unroll
        for (int mi = 0; mi < 2; mi++) {
          Oacc[mi][nt] = MFMA16(ap[mi][0], bv0, Oacc[mi][nt]);
          Oacc[mi][nt] = MFMA16(ap[mi][1], bv1, Oacc[mi][nt]);
        }
      }
    }
  }

#pragma unroll
  for (int mi = 0; mi < 2; mi++)
#pragma unroll
    for (int r = 0; r < 4; r++) {
      const float lv = __shfl(lacc[mi][r], lane & 48, 64);
      const float invl = 1.0f / lv;
      const int t = q0 + wave * 32 + mi * 16 + quad * 4 + r;
#pragma unroll
      for (int nt = 0; nt < 4; nt++)
        base[(size_t)t * N_QKV + nt * 16 + l15] =
            (bf16)(Oacc[mi][nt][r] * invl);
    }
}

// -------------------- launch --------------------
extern "C" void kernel_launch(void* const* d_in, const int* in_sizes, int n_in,
                              void* d_out, int out_size, void* d_ws, size_t ws_size,
                              hipStream_t stream) {
  const void* x = d_in[0];       // [8192,1024] fp32 or bf16
  const void* w_qkv = d_in[1];   // [1024,3072]
  const void* w_out = d_in[2];   // [1024,1024]
  const void* b_out = d_in[3];   // [1024]

  int* flag = (int*)d_ws;
  char* p = (char*)d_ws + 256;
  bf16* wqkvT = (bf16*)p;                          // [3072,1024]  6 MB
  bf16* woutT = wqkvT + (size_t)N_QKV * CC;        // [1024,1024]  2 MB

  const size_t wT_bytes = ((size_t)N_QKV * CC + (size_t)CC * CC) * 2;  // 8 MB
  const size_t qkv_bytes = (size_t)MM * N_QKV * 2;                     // 48 MB
  const size_t need_A = 256 + wT_bytes + qkv_bytes;                    // 56.25 MB
  const size_t need_B = 256 + wT_bytes + (size_t)TT * N_QKV * 2;

  sniff_k<<<1, 256, 0, stream>>>((const unsigned short*)x, flag);

  if (ws_size >= need_A) {
    // ---- Tier A: fused; qkv GEMM path adapts to available slack ----
    bf16* qkv = woutT + (size_t)CC * CC;
    bf16* xb = qkv + (size_t)MM * N_QKV;
    const size_t slack = ws_size - need_A;

    const size_t full_xb = (size_t)MM * CC * 2;    // 16 MB
    const size_t half_xb = full_xb / 2;            // 8 MB
    if (slack >= full_xb) {
      // fused prep (transposes + cvt), 256^2 GEMM, vt, verified attn
      prep_k<<<4096 + (MM * CC) / 2048, 256, 0, stream>>>(
          x, xb, w_qkv, wqkvT, w_out, woutT, flag);
      gemm_q<<<dim3((MM / 256) * (N_QKV / 256)), 512, 0, stream>>>(
          xb, wqkvT, qkv, MM, N_QKV, CC, CC, N_QKV);
      bf16* vt = xb;   // xb dead after the GEMM; same 16 MB size
      vtrans_k<<<dim3(TT / 32, DD / 32, BB * HH), 256, 0, stream>>>(qkv, vt);
      attn_k<<<dim3(BB * HH, 16), 256, 0, stream>>>(qkv, vt);
    } else if (slack >= half_xb) {
      prep_k<<<4096, 256, 0, stream>>>(x, nullptr, w_qkv, wqkvT, w_out, woutT, flag);
      for (int m0 = 0; m0 < MM; m0 += 4096) {
        cvt_k<<<(4096 * CC) / 2048, 256, 0, stream>>>(x, xb, flag, (size_t)m0 * CC);
        gemm_lds<0><<<dim3(4096 / 128, N_QKV / 128), 256, 0, stream>>>(
            xb, wqkvT, nullptr, qkv, flag, 0, (size_t)m0 * N_QKV,
            4096, N_QKV, CC, CC, N_QKV);
      }
      attn_s<<<dim3(BB * HH, 16), 256, 0, stream>>>(qkv);
    } else {
      prep_k<<<4096, 256, 0, stream>>>(x, nullptr, w_qkv, wqkvT, w_out, woutT, flag);
      gemm_bt<0, true><<<dim3(MM / 128, N_QKV / 128), 256, 0, stream>>>(
          x, wqkvT, nullptr, qkv, flag, 0, 0, MM, N_QKV, CC, CC, N_QKV);
      attn_s<<<dim3(BB * HH, 16), 256, 0, stream>>>(qkv);
    }

    gemm8p2<1><<<dim3((MM / 256) * (CC / 128)), 512, 0, stream>>>(
        qkv, woutT, b_out, d_out, flag, MM, CC, CC, N_QKV, CC);
  } else if (ws_size >= need_B) {
    // ---- Tier B: per-batch, pre-transposed weights ----
    bf16* qkv = woutT + (size_t)CC * CC;
    prep_k<<<4096, 256, 0, stream>>>(x, nullptr, w_qkv, wqkvT, w_out, woutT, flag);
    for (int b = 0; b < BB; b++) {
      const size_t xoff = (size_t)b * TT * CC;
      gemm_bt<0, true><<<dim3(TT / 128, N_QKV / 128), 256, 0, stream>>>(
          x, wqkvT, nullptr, qkv, flag, xoff, 0, TT, N_QKV, CC, CC, N_QKV);
      attn_s<<<dim3(HH, 16), 256, 0, stream>>>(qkv);
      gemm_lds<1><<<dim3(TT / 128, CC / 128), 256, 0, stream>>>(
          qkv, woutT, b_out, d_out, flag, 0, xoff, TT, CC, CC, N_QKV, CC);
    }
  } else {
    // ---- Tier C: minimal ws ----
    bf16* qkvb = (bf16*)p;
    for (int b = 0; b < BB; b++) {
      const size_t xoff = (size_t)b * TT * CC;
      gemm_nt<0, true, true><<<dim3(TT / 128, N_QKV / 128), 256, 0, stream>>>(
          x, w_qkv, nullptr, qkvb, flag, xoff, 0, TT, N_QKV, CC, CC, N_QKV);
      attn_s<<<dim3(HH, 16), 256, 0, stream>>>(qkvb);
      gemm_nt<1, false, true><<<dim3(TT / 128, CC / 128), 256, 0, stream>>>(
          qkvb, w_out, b_out, d_out, flag, 0, xoff, TT, CC, CC, N_QKV, CC);
    }
  }
}